// Round 1
// baseline (1245.001 us; speedup 1.0000x reference)
//
#include <hip/hip_runtime.h>
#include <stdint.h>

// ---- problem constants (from setup_inputs) ----
#define NIMG 16
#define AANCH 3
#define HH 256
#define WW 336
#define HWP (HH*WW)            // 86016
#define NUM (AANCH*HWP)        // 258048 anchors per image
#define TOTAL (NIMG*NUM)       // 4128768
#define PRE_K 2000
#define POST_K 1000
#define NMS_TH 0.7f
#define NEGV -1e30f
#define CAND_CAP 4096
#define ROWS 2048              // padded row count for top-2000 arrays
#define RWORDS 64              // 32-bit mask words per NMS row (64*32 = 2048 bits)

// ---- workspace layout (bytes) ----
#define WS_HIST 0u             // 16 * 65536 * 4      = 4194304
#define WS_CUT  4194304u       // 16 * 4  (pad 256)
#define WS_CNT  4194560u       // 16 * 4  (pad 256)
#define WS_CAND 4194816u       // 16 * 4096 * 8       = 524288
#define WS_BOX  4719104u       // 16 * 2048 * 16      = 524288
#define WS_SCO  5243392u       // 16 * 2048 * 4       = 131072
#define WS_RMI  5374464u       // 16 * 64 * 4         = 4096
#define WS_SEL  5378560u       // 16 * 1024 * 4       = 65536
#define WS_MASK 5444096u       // 16 * 2048 * 64 * 4  = 8388608
// total ~13.8 MB

// monotonic float -> uint key (descending float == descending key)
__device__ __forceinline__ uint32_t fkey(float f){
    uint32_t b = __float_as_uint(f);
    return (b & 0x80000000u) ? ~b : (b | 0x80000000u);
}
__device__ __forceinline__ float keyf(uint32_t k){
    uint32_t b = (k & 0x80000000u) ? (k & 0x7FFFFFFFu) : ~k;
    return __uint_as_float(b);
}

// ---- zero the counters (hist + cut + cnt region, and rminit) ----
__global__ void k_zero(uint32_t* ws32){
    const int n1 = (int)(WS_CAND / 4);         // words [0, WS_CAND): hist+cut+cnt
    const int n2 = NIMG * RWORDS;              // rminit words
    int stride = gridDim.x * blockDim.x;
    for (int i = blockIdx.x * blockDim.x + threadIdx.x; i < n1 + n2; i += stride){
        if (i < n1) ws32[i] = 0u;
        else        ws32[(WS_RMI / 4) + (i - n1)] = 0u;
    }
}

// ---- 65536-bin histogram of score keys, per image ----
__global__ void k_hist(const float* __restrict__ obj, uint32_t* __restrict__ hist){
    int stride = gridDim.x * blockDim.x;
    for (int t = blockIdx.x * blockDim.x + threadIdx.x; t < TOTAL; t += stride){
        int img = t / NUM;
        uint32_t k = fkey(obj[t]);
        atomicAdd(&hist[img * 65536 + (k >> 16)], 1u);
    }
}

// ---- find the bin containing rank PRE_K (from the top); cutoff = bin low edge ----
__global__ __launch_bounds__(1024) void k_binsel(const uint32_t* __restrict__ hist,
                                                 uint32_t* __restrict__ cut){
    int img = blockIdx.x, tid = threadIdx.x;
    const uint32_t* h = hist + img * 65536;
    int base = 65536 - (tid + 1) * 64;   // segment tid covers 64 bins, tid=0 = topmost
    uint32_t s = 0;
    for (int b = 0; b < 64; ++b) s += h[base + b];
    __shared__ uint32_t ss[1024];
    uint32_t x = s;
    ss[tid] = x; __syncthreads();
    for (int d = 1; d < 1024; d <<= 1){
        uint32_t y = (tid >= d) ? ss[tid - d] : 0u;
        __syncthreads();
        x += y; ss[tid] = x;
        __syncthreads();
    }
    uint32_t incl = x, excl = x - s;
    if (excl < PRE_K && incl >= PRE_K){
        uint32_t c = excl;
        for (int b = 63; b >= 0; --b){          // walk bins descending by value
            c += h[base + b];
            if (c >= PRE_K){ cut[img] = ((uint32_t)(base + b)) << 16; break; }
        }
    }
}

// ---- compact candidates (key >= cutoff) with original flat score index ----
__global__ void k_compact(const float* __restrict__ obj, const uint32_t* __restrict__ cut,
                          uint32_t* __restrict__ cnt, unsigned long long* __restrict__ cand){
    int stride = gridDim.x * blockDim.x;
    for (int t = blockIdx.x * blockDim.x + threadIdx.x; t < TOTAL; t += stride){
        int img = t / NUM;
        int r = t - img * NUM;                 // linear (a,h,w) index inside image
        uint32_t k = fkey(obj[t]);
        if (k >= cut[img]){
            uint32_t pos = atomicAdd(&cnt[img], 1u);
            if (pos < CAND_CAP){
                int a = r / HWP, hw = r - a * HWP;
                uint32_t f = (uint32_t)(hw * AANCH + a);   // permute_and_flatten index
                cand[img * CAND_CAP + pos] =
                    ((unsigned long long)k << 32) | (uint32_t)(~f);
            }
        }
    }
}

// ---- bitonic sort candidates desc, take top-2000, gather+decode+clip ----
__global__ __launch_bounds__(1024) void k_sortdecode(
        const unsigned long long* __restrict__ cand, const uint32_t* __restrict__ cnt,
        const float* __restrict__ anchors, const float* __restrict__ breg,
        const int* __restrict__ pimh, const int* __restrict__ pimw,
        float4* __restrict__ boxes_s, float* __restrict__ scores_s,
        uint32_t* __restrict__ rminit){
    int img = blockIdx.x, tid = threadIdx.x;
    __shared__ unsigned long long sd[CAND_CAP];
    uint32_t cl = min(cnt[img], (uint32_t)CAND_CAP);
    for (int t = tid; t < CAND_CAP; t += 1024)
        sd[t] = (t < (int)cl) ? cand[img * CAND_CAP + t] : 0ull;
    __syncthreads();
    for (uint32_t k = 2; k <= CAND_CAP; k <<= 1){
        for (uint32_t j = k >> 1; j > 0; j >>= 1){
            for (int t = tid; t < CAND_CAP; t += 1024){
                int ixj = t ^ (int)j;
                if (ixj > t){
                    unsigned long long a = sd[t], b = sd[ixj];
                    bool up = ((t & k) == 0);   // descending overall
                    if (up ? (a < b) : (a > b)){ sd[t] = b; sd[ixj] = a; }
                }
            }
            __syncthreads();
        }
    }
    float imw = (float)(*pimw), imh = (float)(*pimh);
    const float CLIPV = 4.135166556742356f;     // log(1000/16)
    for (int t = tid; t < PRE_K; t += 1024){
        unsigned long long comp = sd[t];
        uint32_t key = (uint32_t)(comp >> 32);
        uint32_t f = ~(uint32_t)comp;
        float logit = keyf(key);
        float sc = 1.0f / (1.0f + expf(-logit));
        const float* an = anchors + ((size_t)img * NUM + f) * 4;
        float ax1 = an[0], ay1 = an[1], ax2 = an[2], ay2 = an[3];
        int a = (int)(f % AANCH); int hw = (int)(f / AANCH);
        int h = hw / WW; int w = hw - h * WW;
        size_t bbase = ((size_t)img * 12 + a * 4) * HWP + (size_t)h * WW + w;
        float dx = breg[bbase], dy = breg[bbase + HWP];
        float dw = breg[bbase + 2 * (size_t)HWP], dh = breg[bbase + 3 * (size_t)HWP];
        float aw = ax2 - ax1 + 1.0f, ah = ay2 - ay1 + 1.0f;
        float cx = ax1 + 0.5f * aw, cy = ay1 + 0.5f * ah;
        dw = fminf(dw, CLIPV); dh = fminf(dh, CLIPV);
        float pcx = dx * aw + cx, pcy = dy * ah + cy;
        float pw = expf(dw) * aw, ph = expf(dh) * ah;
        float x1 = pcx - 0.5f * pw, y1 = pcy - 0.5f * ph;
        float x2 = pcx + 0.5f * pw - 1.0f, y2 = pcy + 0.5f * ph - 1.0f;
        x1 = fminf(fmaxf(x1, 0.0f), imw - 1.0f);
        y1 = fminf(fmaxf(y1, 0.0f), imh - 1.0f);
        x2 = fminf(fmaxf(x2, 0.0f), imw - 1.0f);
        y2 = fminf(fmaxf(y2, 0.0f), imh - 1.0f);
        bool valid = ((x2 - x1 + 1.0f) >= 0.0f) && ((y2 - y1 + 1.0f) >= 0.0f);
        boxes_s[img * ROWS + t] = make_float4(x1, y1, x2, y2);
        scores_s[img * ROWS + t] = sc;
        if (!valid) atomicOr(&rminit[img * RWORDS + (t >> 5)], 1u << (t & 31));
    }
}

// ---- build upper-triangle IoU>thresh bitmask rows ----
__global__ __launch_bounds__(1024) void k_mask(const float4* __restrict__ boxes_s,
                                               uint32_t* __restrict__ mask){
    int img = blockIdx.x >> 3;
    int rc  = blockIdx.x & 7;
    int tid = threadIdx.x;
    __shared__ float4 B[PRE_K];
    __shared__ float  AR[PRE_K];
    const float4* bp = boxes_s + img * ROWS;
    for (int t = tid; t < PRE_K; t += 1024){
        float4 b = bp[t]; B[t] = b;
        AR[t] = (b.z - b.x + 1.0f) * (b.w - b.y + 1.0f);
    }
    __syncthreads();
    uint32_t* M = mask + (size_t)img * ROWS * RWORDS;
    int rowbase = rc * 250;
    for (int task = tid; task < 250 * 64; task += 1024){
        int i = rowbase + (task >> 6);
        int w = task & 63;
        if (w < (i >> 5)) continue;            // fully below diagonal: never read
        float4 bi = B[i]; float ai = AR[i];
        uint32_t bits = 0;
        int j0 = w * 32;
        int jlo = max(j0, i + 1), jhi = min(j0 + 32, PRE_K);
        for (int j = jlo; j < jhi; ++j){
            float4 bj = B[j];
            float xx1 = fmaxf(bi.x, bj.x), yy1 = fmaxf(bi.y, bj.y);
            float xx2 = fminf(bi.z, bj.z), yy2 = fminf(bi.w, bj.w);
            float iw = fmaxf(xx2 - xx1 + 1.0f, 0.0f);
            float ih = fmaxf(yy2 - yy1 + 1.0f, 0.0f);
            float inter = iw * ih;
            float iou = inter / (ai + AR[j] - inter);
            if (iou > NMS_TH) bits |= (1u << (j - j0));
        }
        M[(size_t)i * RWORDS + w] = bits;
    }
}

// ---- serial greedy NMS scan (1 wave per image) + compaction of kept list ----
__global__ __launch_bounds__(64) void k_scan(const uint32_t* __restrict__ mask,
                                             const uint32_t* __restrict__ rminit,
                                             uint32_t* __restrict__ sel){
    int img = blockIdx.x; int lane = threadIdx.x;
    const uint32_t* M = mask + (size_t)img * ROWS * RWORDS;
    uint32_t rm = rminit[img * RWORDS + lane];   // invalid boxes start removed
    uint32_t b0 = M[0 * 64 + lane], b1 = M[1 * 64 + lane];
    uint32_t b2 = M[2 * 64 + lane], b3 = M[3 * 64 + lane];
#define STEP(I, BUF) { int w_ = (I) >> 5; uint32_t wd_ = __shfl(rm, w_);            \
        if (!((wd_ >> ((I) & 31)) & 1u) && lane >= w_) rm |= BUF;                    \
        BUF = M[((I) + 4) * 64 + lane]; }
    for (int i = 0; i < PRE_K; i += 4){
        STEP(i, b0); STEP(i + 1, b1); STEP(i + 2, b2); STEP(i + 3, b3);
    }
#undef STEP
    // kept = ~removed within [0, PRE_K)
    uint32_t inr = (lane < 62) ? 0xFFFFFFFFu : (lane == 62 ? 0x0000FFFFu : 0u);
    uint32_t kw = (~rm) & inr;
    uint32_t sw = rm & inr;
    uint32_t kc = __popc(kw);
    uint32_t x = kc;
    for (int d = 1; d < 64; d <<= 1){ uint32_t y = __shfl_up(x, d); if (lane >= d) x += y; }
    uint32_t kexcl = x - kc;
    uint32_t ktot = __shfl(x, 63);
    uint32_t* S = sel + img * 1024;
    uint32_t m = kw; uint32_t r = 0;
    while (m){
        int b = __ffs(m) - 1;
        uint32_t slot = kexcl + r;
        if (slot < POST_K) S[slot] = (uint32_t)(lane * 32 + b) | 0x80000000u;
        m &= m - 1; ++r;
    }
    if (ktot < POST_K){   // pad with suppressed positions in index order, score NEG
        uint32_t sc2 = __popc(sw);
        uint32_t x2 = sc2;
        for (int d = 1; d < 64; d <<= 1){ uint32_t y = __shfl_up(x2, d); if (lane >= d) x2 += y; }
        uint32_t sexcl = x2 - sc2;
        uint32_t m2 = sw; uint32_t r2 = 0;
        while (m2){
            int b = __ffs(m2) - 1;
            uint32_t slot = ktot + sexcl + r2;
            if (slot >= ktot && slot < POST_K) S[slot] = (uint32_t)(lane * 32 + b);
            m2 &= m2 - 1; ++r2;
        }
    }
}

// ---- write [N, 1000, 5] output ----
__global__ void k_out(const uint32_t* __restrict__ sel, const float4* __restrict__ boxes_s,
                      const float* __restrict__ scores_s, float* __restrict__ out){
    int t = blockIdx.x * blockDim.x + threadIdx.x;
    if (t >= NIMG * POST_K) return;
    int img = t / POST_K, s = t - img * POST_K;
    uint32_t v = sel[img * 1024 + s];
    uint32_t pos = v & 0x7FFFFFFFu;
    bool kept = (v >> 31) != 0;
    float4 b = boxes_s[img * ROWS + pos];
    float sc = kept ? scores_s[img * ROWS + pos] : NEGV;
    float* o = out + (size_t)t * 5;
    o[0] = b.x; o[1] = b.y; o[2] = b.z; o[3] = b.w; o[4] = sc;
}

extern "C" void kernel_launch(void* const* d_in, const int* in_sizes, int n_in,
                              void* d_out, int out_size, void* d_ws, size_t ws_size,
                              hipStream_t stream) {
    const float* anchors = (const float*)d_in[0];
    const float* obj     = (const float*)d_in[1];
    const float* breg    = (const float*)d_in[2];
    const int*   pimh    = (const int*)d_in[3];
    const int*   pimw    = (const int*)d_in[4];
    float* out = (float*)d_out;
    uint8_t* ws = (uint8_t*)d_ws;

    uint32_t*           hist     = (uint32_t*)(ws + WS_HIST);
    uint32_t*           cut      = (uint32_t*)(ws + WS_CUT);
    uint32_t*           cnt      = (uint32_t*)(ws + WS_CNT);
    unsigned long long* cand     = (unsigned long long*)(ws + WS_CAND);
    float4*             boxes_s  = (float4*)(ws + WS_BOX);
    float*              scores_s = (float*)(ws + WS_SCO);
    uint32_t*           rminit   = (uint32_t*)(ws + WS_RMI);
    uint32_t*           sel      = (uint32_t*)(ws + WS_SEL);
    uint32_t*           mask     = (uint32_t*)(ws + WS_MASK);

    k_zero<<<1024, 256, 0, stream>>>((uint32_t*)ws);
    k_hist<<<2048, 256, 0, stream>>>(obj, hist);
    k_binsel<<<NIMG, 1024, 0, stream>>>(hist, cut);
    k_compact<<<2048, 256, 0, stream>>>(obj, cut, cnt, cand);
    k_sortdecode<<<NIMG, 1024, 0, stream>>>(cand, cnt, anchors, breg, pimh, pimw,
                                            boxes_s, scores_s, rminit);
    k_mask<<<NIMG * 8, 1024, 0, stream>>>(boxes_s, mask);
    k_scan<<<NIMG, 64, 0, stream>>>(mask, rminit, sel);
    k_out<<<(NIMG * POST_K + 255) / 256, 256, 0, stream>>>(sel, boxes_s, scores_s, out);
}

// Round 2
// 878.099 us; speedup vs baseline: 1.4178x; 1.4178x over previous
//
#include <hip/hip_runtime.h>
#include <stdint.h>

// ---- problem constants (from setup_inputs) ----
#define NIMG 16
#define AANCH 3
#define HH 256
#define WW 336
#define HWP (HH*WW)            // 86016
#define NUM (AANCH*HWP)        // 258048 anchors per image
#define TOTAL (NIMG*NUM)       // 4128768
#define PRE_K 2000
#define POST_K 1000
#define NMS_TH 0.7f
#define NEGV -1e30f
#define CAND_CAP 4096
#define ROWS 2048              // padded row count for top-2000 arrays
#define RWORDS 64              // 32-bit mask words per NMS row (64*32 = 2048 bits)

// ---- workspace layout (bytes) ----
#define WS_HIST 0u             // 16 * 65536 * 4      = 4194304
#define WS_CUT  4194304u       // 16 * 4  (pad 256)
#define WS_CNT  4194560u       // 16 * 4  (pad 256)
#define WS_CAND 4194816u       // 16 * 4096 * 8       = 524288
#define WS_BOX  4719104u       // 16 * 2048 * 16      = 524288
#define WS_SCO  5243392u       // 16 * 2048 * 4       = 131072
#define WS_RMI  5374464u       // 16 * 64 * 4         = 4096
#define WS_SEL  5378560u       // 16 * 1024 * 4       = 65536
#define WS_MASK 5444096u       // 16 * 2048 * 64 * 4  = 8388608
// total ~13.8 MB

// monotonic float -> uint key (descending float == descending key)
__device__ __forceinline__ uint32_t fkey(float f){
    uint32_t b = __float_as_uint(f);
    return (b & 0x80000000u) ? ~b : (b | 0x80000000u);
}
__device__ __forceinline__ float keyf(uint32_t k){
    uint32_t b = (k & 0x80000000u) ? (k & 0x7FFFFFFFu) : ~k;
    return __uint_as_float(b);
}

// ---- zero the counters (hist + cut + cnt region, and rminit) ----
__global__ void k_zero(uint32_t* ws32){
    const int n1 = (int)(WS_CAND / 4);         // words [0, WS_CAND): hist+cut+cnt
    const int n2 = NIMG * RWORDS;              // rminit words
    int stride = gridDim.x * blockDim.x;
    for (int i = blockIdx.x * blockDim.x + threadIdx.x; i < n1 + n2; i += stride){
        if (i < n1) ws32[i] = 0u;
        else        ws32[(WS_RMI / 4) + (i - n1)] = 0u;
    }
}

// ---- 65536-bin histogram of score keys, per image ----
__global__ void k_hist(const float* __restrict__ obj, uint32_t* __restrict__ hist){
    int stride = gridDim.x * blockDim.x;
    for (int t = blockIdx.x * blockDim.x + threadIdx.x; t < TOTAL; t += stride){
        int img = t / NUM;
        uint32_t k = fkey(obj[t]);
        atomicAdd(&hist[img * 65536 + (k >> 16)], 1u);
    }
}

// ---- find the bin containing rank PRE_K (from the top); cutoff = bin low edge ----
__global__ __launch_bounds__(1024) void k_binsel(const uint32_t* __restrict__ hist,
                                                 uint32_t* __restrict__ cut){
    int img = blockIdx.x, tid = threadIdx.x;
    const uint32_t* h = hist + img * 65536;
    int base = 65536 - (tid + 1) * 64;   // segment tid covers 64 bins, tid=0 = topmost
    uint32_t s = 0;
    for (int b = 0; b < 64; ++b) s += h[base + b];
    __shared__ uint32_t ss[1024];
    uint32_t x = s;
    ss[tid] = x; __syncthreads();
    for (int d = 1; d < 1024; d <<= 1){
        uint32_t y = (tid >= d) ? ss[tid - d] : 0u;
        __syncthreads();
        x += y; ss[tid] = x;
        __syncthreads();
    }
    uint32_t incl = x, excl = x - s;
    if (excl < PRE_K && incl >= PRE_K){
        uint32_t c = excl;
        for (int b = 63; b >= 0; --b){          // walk bins descending by value
            c += h[base + b];
            if (c >= PRE_K){ cut[img] = ((uint32_t)(base + b)) << 16; break; }
        }
    }
}

// ---- compact candidates (key >= cutoff) with original flat score index ----
__global__ void k_compact(const float* __restrict__ obj, const uint32_t* __restrict__ cut,
                          uint32_t* __restrict__ cnt, unsigned long long* __restrict__ cand){
    int stride = gridDim.x * blockDim.x;
    for (int t = blockIdx.x * blockDim.x + threadIdx.x; t < TOTAL; t += stride){
        int img = t / NUM;
        int r = t - img * NUM;                 // linear (a,h,w) index inside image
        uint32_t k = fkey(obj[t]);
        if (k >= cut[img]){
            uint32_t pos = atomicAdd(&cnt[img], 1u);
            if (pos < CAND_CAP){
                int a = r / HWP, hw = r - a * HWP;
                uint32_t f = (uint32_t)(hw * AANCH + a);   // permute_and_flatten index
                cand[img * CAND_CAP + pos] =
                    ((unsigned long long)k << 32) | (uint32_t)(~f);
            }
        }
    }
}

// ---- bitonic sort candidates desc, take top-2000, gather+decode+clip ----
__global__ __launch_bounds__(1024) void k_sortdecode(
        const unsigned long long* __restrict__ cand, const uint32_t* __restrict__ cnt,
        const float* __restrict__ anchors, const float* __restrict__ breg,
        const int* __restrict__ pimh, const int* __restrict__ pimw,
        float4* __restrict__ boxes_s, float* __restrict__ scores_s,
        uint32_t* __restrict__ rminit){
    int img = blockIdx.x, tid = threadIdx.x;
    __shared__ unsigned long long sd[CAND_CAP];
    uint32_t cl = min(cnt[img], (uint32_t)CAND_CAP);
    for (int t = tid; t < CAND_CAP; t += 1024)
        sd[t] = (t < (int)cl) ? cand[img * CAND_CAP + t] : 0ull;
    __syncthreads();
    for (uint32_t k = 2; k <= CAND_CAP; k <<= 1){
        for (uint32_t j = k >> 1; j > 0; j >>= 1){
            for (int t = tid; t < CAND_CAP; t += 1024){
                int ixj = t ^ (int)j;
                if (ixj > t){
                    unsigned long long a = sd[t], b = sd[ixj];
                    bool up = ((t & k) == 0);   // descending overall
                    if (up ? (a < b) : (a > b)){ sd[t] = b; sd[ixj] = a; }
                }
            }
            __syncthreads();
        }
    }
    float imw = (float)(*pimw), imh = (float)(*pimh);
    const float CLIPV = 4.135166556742356f;     // log(1000/16)
    for (int t = tid; t < PRE_K; t += 1024){
        unsigned long long comp = sd[t];
        uint32_t key = (uint32_t)(comp >> 32);
        uint32_t f = ~(uint32_t)comp;
        float logit = keyf(key);
        float sc = 1.0f / (1.0f + expf(-logit));
        const float* an = anchors + ((size_t)img * NUM + f) * 4;
        float ax1 = an[0], ay1 = an[1], ax2 = an[2], ay2 = an[3];
        int a = (int)(f % AANCH); int hw = (int)(f / AANCH);
        int h = hw / WW; int w = hw - h * WW;
        size_t bbase = ((size_t)img * 12 + a * 4) * HWP + (size_t)h * WW + w;
        float dx = breg[bbase], dy = breg[bbase + HWP];
        float dw = breg[bbase + 2 * (size_t)HWP], dh = breg[bbase + 3 * (size_t)HWP];
        float aw = ax2 - ax1 + 1.0f, ah = ay2 - ay1 + 1.0f;
        float cx = ax1 + 0.5f * aw, cy = ay1 + 0.5f * ah;
        dw = fminf(dw, CLIPV); dh = fminf(dh, CLIPV);
        float pcx = dx * aw + cx, pcy = dy * ah + cy;
        float pw = expf(dw) * aw, ph = expf(dh) * ah;
        float x1 = pcx - 0.5f * pw, y1 = pcy - 0.5f * ph;
        float x2 = pcx + 0.5f * pw - 1.0f, y2 = pcy + 0.5f * ph - 1.0f;
        x1 = fminf(fmaxf(x1, 0.0f), imw - 1.0f);
        y1 = fminf(fmaxf(y1, 0.0f), imh - 1.0f);
        x2 = fminf(fmaxf(x2, 0.0f), imw - 1.0f);
        y2 = fminf(fmaxf(y2, 0.0f), imh - 1.0f);
        bool valid = ((x2 - x1 + 1.0f) >= 0.0f) && ((y2 - y1 + 1.0f) >= 0.0f);
        boxes_s[img * ROWS + t] = make_float4(x1, y1, x2, y2);
        scores_s[img * ROWS + t] = sc;
        if (!valid) atomicOr(&rminit[img * RWORDS + (t >> 5)], 1u << (t & 31));
    }
}

// ---- build upper-triangle IoU>thresh bitmask rows ----
// One wave per row-slice: lanes cover 64 consecutive j (conflict-free LDS reads),
// mask via __ballot, one uint64 store per 64-j block.
__global__ __launch_bounds__(1024) void k_mask(const float4* __restrict__ boxes_s,
                                               uint32_t* __restrict__ mask){
    int img = blockIdx.x >> 4;                 // 16 blocks per image
    int rc  = blockIdx.x & 15;
    int tid = threadIdx.x;
    int lane = tid & 63;
    int wv = tid >> 6;                         // 16 waves per block
    int gw = rc * 16 + wv;                     // 0..255 wave slot within image
    __shared__ float4 B[PRE_K];
    __shared__ float  AR[PRE_K];
    const float4* bp = boxes_s + img * ROWS;
    for (int t = tid; t < PRE_K; t += 1024){
        float4 b = bp[t]; B[t] = b;
        AR[t] = (b.z - b.x + 1.0f) * (b.w - b.y + 1.0f);
    }
    __syncthreads();
    uint32_t* M = mask + (size_t)img * ROWS * RWORDS;
    for (int i = gw; i < PRE_K; i += 256){
        float4 bi = B[i];                      // same address across wave: broadcast
        float ai = AR[i];
        unsigned long long* Mrow = (unsigned long long*)(M + (size_t)i * RWORDS);
        for (int jb = (i >> 6); jb < 32; ++jb){
            int j = (jb << 6) + lane;
            bool pred = false;
            if (j > i && j < PRE_K){
                float4 bj = B[j];
                float xx1 = fmaxf(bi.x, bj.x), yy1 = fmaxf(bi.y, bj.y);
                float xx2 = fminf(bi.z, bj.z), yy2 = fminf(bi.w, bj.w);
                float iw = fmaxf(xx2 - xx1 + 1.0f, 0.0f);
                float ih = fmaxf(yy2 - yy1 + 1.0f, 0.0f);
                float inter = iw * ih;
                pred = inter > NMS_TH * (ai + AR[j] - inter);
            }
            unsigned long long bm = __ballot(pred);
            if (lane == 0) Mrow[jb] = bm;
        }
    }
}

// ---- serial greedy NMS scan (1 wave per image) + compaction of kept list ----
__global__ __launch_bounds__(64) void k_scan(const uint32_t* __restrict__ mask,
                                             const uint32_t* __restrict__ rminit,
                                             uint32_t* __restrict__ sel){
    int img = blockIdx.x; int lane = threadIdx.x;
    const uint32_t* M = mask + (size_t)img * ROWS * RWORDS;
    uint32_t rm = rminit[img * RWORDS + lane];   // invalid boxes start removed
    uint32_t b0 = M[0 * 64 + lane], b1 = M[1 * 64 + lane];
    uint32_t b2 = M[2 * 64 + lane], b3 = M[3 * 64 + lane];
#define STEP(I, BUF) { int w_ = (I) >> 5; uint32_t wd_ = __shfl(rm, w_);            \
        if (!((wd_ >> ((I) & 31)) & 1u) && lane >= w_) rm |= BUF;                    \
        BUF = M[((I) + 4) * 64 + lane]; }
    for (int i = 0; i < PRE_K; i += 4){
        STEP(i, b0); STEP(i + 1, b1); STEP(i + 2, b2); STEP(i + 3, b3);
    }
#undef STEP
    // kept = ~removed within [0, PRE_K)
    uint32_t inr = (lane < 62) ? 0xFFFFFFFFu : (lane == 62 ? 0x0000FFFFu : 0u);
    uint32_t kw = (~rm) & inr;
    uint32_t sw = rm & inr;
    uint32_t kc = __popc(kw);
    uint32_t x = kc;
    for (int d = 1; d < 64; d <<= 1){ uint32_t y = __shfl_up(x, d); if (lane >= d) x += y; }
    uint32_t kexcl = x - kc;
    uint32_t ktot = __shfl(x, 63);
    uint32_t* S = sel + img * 1024;
    uint32_t m = kw; uint32_t r = 0;
    while (m){
        int b = __ffs(m) - 1;
        uint32_t slot = kexcl + r;
        if (slot < POST_K) S[slot] = (uint32_t)(lane * 32 + b) | 0x80000000u;
        m &= m - 1; ++r;
    }
    if (ktot < POST_K){   // pad with suppressed positions in index order, score NEG
        uint32_t sc2 = __popc(sw);
        uint32_t x2 = sc2;
        for (int d = 1; d < 64; d <<= 1){ uint32_t y = __shfl_up(x2, d); if (lane >= d) x2 += y; }
        uint32_t sexcl = x2 - sc2;
        uint32_t m2 = sw; uint32_t r2 = 0;
        while (m2){
            int b = __ffs(m2) - 1;
            uint32_t slot = ktot + sexcl + r2;
            if (slot >= ktot && slot < POST_K) S[slot] = (uint32_t)(lane * 32 + b);
            m2 &= m2 - 1; ++r2;
        }
    }
}

// ---- write [N, 1000, 5] output ----
__global__ void k_out(const uint32_t* __restrict__ sel, const float4* __restrict__ boxes_s,
                      const float* __restrict__ scores_s, float* __restrict__ out){
    int t = blockIdx.x * blockDim.x + threadIdx.x;
    if (t >= NIMG * POST_K) return;
    int img = t / POST_K, s = t - img * POST_K;
    uint32_t v = sel[img * 1024 + s];
    uint32_t pos = v & 0x7FFFFFFFu;
    bool kept = (v >> 31) != 0;
    float4 b = boxes_s[img * ROWS + pos];
    float sc = kept ? scores_s[img * ROWS + pos] : NEGV;
    float* o = out + (size_t)t * 5;
    o[0] = b.x; o[1] = b.y; o[2] = b.z; o[3] = b.w; o[4] = sc;
}

extern "C" void kernel_launch(void* const* d_in, const int* in_sizes, int n_in,
                              void* d_out, int out_size, void* d_ws, size_t ws_size,
                              hipStream_t stream) {
    const float* anchors = (const float*)d_in[0];
    const float* obj     = (const float*)d_in[1];
    const float* breg    = (const float*)d_in[2];
    const int*   pimh    = (const int*)d_in[3];
    const int*   pimw    = (const int*)d_in[4];
    float* out = (float*)d_out;
    uint8_t* ws = (uint8_t*)d_ws;

    uint32_t*           hist     = (uint32_t*)(ws + WS_HIST);
    uint32_t*           cut      = (uint32_t*)(ws + WS_CUT);
    uint32_t*           cnt      = (uint32_t*)(ws + WS_CNT);
    unsigned long long* cand     = (unsigned long long*)(ws + WS_CAND);
    float4*             boxes_s  = (float4*)(ws + WS_BOX);
    float*              scores_s = (float*)(ws + WS_SCO);
    uint32_t*           rminit   = (uint32_t*)(ws + WS_RMI);
    uint32_t*           sel      = (uint32_t*)(ws + WS_SEL);
    uint32_t*           mask     = (uint32_t*)(ws + WS_MASK);

    k_zero<<<1024, 256, 0, stream>>>((uint32_t*)ws);
    k_hist<<<2048, 256, 0, stream>>>(obj, hist);
    k_binsel<<<NIMG, 1024, 0, stream>>>(hist, cut);
    k_compact<<<2048, 256, 0, stream>>>(obj, cut, cnt, cand);
    k_sortdecode<<<NIMG, 1024, 0, stream>>>(cand, cnt, anchors, breg, pimh, pimw,
                                            boxes_s, scores_s, rminit);
    k_mask<<<NIMG * 16, 1024, 0, stream>>>(boxes_s, mask);
    k_scan<<<NIMG, 64, 0, stream>>>(mask, rminit, sel);
    k_out<<<(NIMG * POST_K + 255) / 256, 256, 0, stream>>>(sel, boxes_s, scores_s, out);
}

// Round 3
// 542.470 us; speedup vs baseline: 2.2951x; 1.6187x over previous
//
#include <hip/hip_runtime.h>
#include <stdint.h>

// ---- problem constants (from setup_inputs) ----
#define NIMG 16
#define AANCH 3
#define HH 256
#define WW 336
#define HWP (HH*WW)            // 86016
#define NUM (AANCH*HWP)        // 258048 anchors per image
#define TOTAL (NIMG*NUM)       // 4128768
#define PRE_K 2000
#define POST_K 1000
#define NMS_TH 0.7f
#define NEGV -1e30f
#define CAND_CAP 4096
#define ROWS 2048              // padded row count for top-2000 arrays
#define RWORDS 64              // 32-bit mask words per NMS row (64*32 = 2048 bits)
#define CHUNK 2048             // elements per k_compact block
#define CBLOCKS (NUM / CHUNK)  // 126 blocks per image

// ---- workspace layout (bytes) ----
#define WS_HIST 0u             // 16 * 65536 * 4      = 4194304
#define WS_CUT  4194304u       // 16 * 4  (pad 256)
#define WS_CNT  4194560u       // 16 * 4  (pad 256)
#define WS_CAND 4194816u       // 16 * 4096 * 8       = 524288
#define WS_BOX  4719104u       // 16 * 2048 * 16      = 524288
#define WS_SCO  5243392u       // 16 * 2048 * 4       = 131072
#define WS_RMI  5374464u       // 16 * 64 * 4         = 4096
#define WS_SEL  5378560u       // 16 * 1024 * 4       = 65536
#define WS_MASK 5444096u       // 16 * 2048 * 64 * 4  = 8388608
// total ~13.8 MB

// monotonic float -> uint key (descending float == descending key)
__device__ __forceinline__ uint32_t fkey(float f){
    uint32_t b = __float_as_uint(f);
    return (b & 0x80000000u) ? ~b : (b | 0x80000000u);
}
__device__ __forceinline__ float keyf(uint32_t k){
    uint32_t b = (k & 0x80000000u) ? (k & 0x7FFFFFFFu) : ~k;
    return __uint_as_float(b);
}

// ---- zero the counters (hist + cut + cnt region, and rminit) ----
__global__ void k_zero(uint32_t* ws32){
    const int n1 = (int)(WS_CAND / 4);         // words [0, WS_CAND): hist+cut+cnt
    const int n2 = NIMG * RWORDS;              // rminit words
    int stride = gridDim.x * blockDim.x;
    for (int i = blockIdx.x * blockDim.x + threadIdx.x; i < n1 + n2; i += stride){
        if (i < n1) ws32[i] = 0u;
        else        ws32[(WS_RMI / 4) + (i - n1)] = 0u;
    }
}

// ---- 65536-bin histogram of score keys, per image ----
__global__ void k_hist(const float* __restrict__ obj, uint32_t* __restrict__ hist){
    int stride = gridDim.x * blockDim.x;
    for (int t = blockIdx.x * blockDim.x + threadIdx.x; t < TOTAL; t += stride){
        int img = t / NUM;
        uint32_t k = fkey(obj[t]);
        atomicAdd(&hist[img * 65536 + (k >> 16)], 1u);
    }
}

// ---- find the bin containing rank PRE_K (from the top); cutoff = bin low edge ----
__global__ __launch_bounds__(1024) void k_binsel(const uint32_t* __restrict__ hist,
                                                 uint32_t* __restrict__ cut){
    int img = blockIdx.x, tid = threadIdx.x;
    const uint32_t* h = hist + img * 65536;
    int base = 65536 - (tid + 1) * 64;   // segment tid covers 64 bins, tid=0 = topmost
    uint32_t s = 0;
    for (int b = 0; b < 64; ++b) s += h[base + b];
    __shared__ uint32_t ss[1024];
    uint32_t x = s;
    ss[tid] = x; __syncthreads();
    for (int d = 1; d < 1024; d <<= 1){
        uint32_t y = (tid >= d) ? ss[tid - d] : 0u;
        __syncthreads();
        x += y; ss[tid] = x;
        __syncthreads();
    }
    uint32_t incl = x, excl = x - s;
    if (excl < PRE_K && incl >= PRE_K){
        uint32_t c = excl;
        for (int b = 63; b >= 0; --b){          // walk bins descending by value
            c += h[base + b];
            if (c >= PRE_K){ cut[img] = ((uint32_t)(base + b)) << 16; break; }
        }
    }
}

// ---- compact candidates (key >= cutoff), block-aggregated atomics ----
__global__ __launch_bounds__(256) void k_compact(const float* __restrict__ obj,
                                                 const uint32_t* __restrict__ cut,
                                                 uint32_t* __restrict__ cnt,
                                                 unsigned long long* __restrict__ cand){
    int img   = blockIdx.x / CBLOCKS;
    int chunk = blockIdx.x - img * CBLOCKS;
    int base  = img * NUM + chunk * CHUNK;     // flat element base
    __shared__ uint32_t lcnt;
    __shared__ uint32_t gbase;
    __shared__ unsigned long long lbuf[CHUNK];
    if (threadIdx.x == 0) lcnt = 0u;
    __syncthreads();
    uint32_t cutv = cut[img];
    #pragma unroll
    for (int it = 0; it < 2; ++it){
        int e = it * 1024 + (int)threadIdx.x * 4;   // element offset within chunk
        float4 v = *(const float4*)(obj + base + e);
        float vv[4] = {v.x, v.y, v.z, v.w};
        #pragma unroll
        for (int q = 0; q < 4; ++q){
            uint32_t k = fkey(vv[q]);
            if (k >= cutv){
                int r = chunk * CHUNK + e + q;       // index within image (a,h,w flat)
                int a = r / HWP, hw = r - a * HWP;
                uint32_t f = (uint32_t)(hw * AANCH + a);  // permute_and_flatten index
                uint32_t p = atomicAdd(&lcnt, 1u);        // LDS atomic: fast
                lbuf[p] = ((unsigned long long)k << 32) | (uint32_t)(~f);
            }
        }
    }
    __syncthreads();
    if (threadIdx.x == 0)
        gbase = (lcnt > 0u) ? atomicAdd(&cnt[img], lcnt) : 0u;  // ONE global atomic/block
    __syncthreads();
    uint32_t n = lcnt, gb = gbase;
    for (uint32_t t = threadIdx.x; t < n; t += 256u){
        uint32_t pos = gb + t;
        if (pos < CAND_CAP) cand[img * CAND_CAP + pos] = lbuf[t];
    }
}

// ---- bitonic sort candidates desc, take top-2000, gather+decode+clip ----
__global__ __launch_bounds__(1024) void k_sortdecode(
        const unsigned long long* __restrict__ cand, const uint32_t* __restrict__ cnt,
        const float* __restrict__ anchors, const float* __restrict__ breg,
        const int* __restrict__ pimh, const int* __restrict__ pimw,
        float4* __restrict__ boxes_s, float* __restrict__ scores_s,
        uint32_t* __restrict__ rminit){
    int img = blockIdx.x, tid = threadIdx.x;
    __shared__ unsigned long long sd[CAND_CAP];
    uint32_t cl = min(cnt[img], (uint32_t)CAND_CAP);
    for (int t = tid; t < CAND_CAP; t += 1024)
        sd[t] = (t < (int)cl) ? cand[img * CAND_CAP + t] : 0ull;
    __syncthreads();
    for (uint32_t k = 2; k <= CAND_CAP; k <<= 1){
        for (uint32_t j = k >> 1; j > 0; j >>= 1){
            for (int t = tid; t < CAND_CAP; t += 1024){
                int ixj = t ^ (int)j;
                if (ixj > t){
                    unsigned long long a = sd[t], b = sd[ixj];
                    bool up = ((t & k) == 0);   // descending overall
                    if (up ? (a < b) : (a > b)){ sd[t] = b; sd[ixj] = a; }
                }
            }
            __syncthreads();
        }
    }
    float imw = (float)(*pimw), imh = (float)(*pimh);
    const float CLIPV = 4.135166556742356f;     // log(1000/16)
    for (int t = tid; t < PRE_K; t += 1024){
        unsigned long long comp = sd[t];
        uint32_t key = (uint32_t)(comp >> 32);
        uint32_t f = ~(uint32_t)comp;
        float logit = keyf(key);
        float sc = 1.0f / (1.0f + expf(-logit));
        const float* an = anchors + ((size_t)img * NUM + f) * 4;
        float ax1 = an[0], ay1 = an[1], ax2 = an[2], ay2 = an[3];
        int a = (int)(f % AANCH); int hw = (int)(f / AANCH);
        int h = hw / WW; int w = hw - h * WW;
        size_t bbase = ((size_t)img * 12 + a * 4) * HWP + (size_t)h * WW + w;
        float dx = breg[bbase], dy = breg[bbase + HWP];
        float dw = breg[bbase + 2 * (size_t)HWP], dh = breg[bbase + 3 * (size_t)HWP];
        float aw = ax2 - ax1 + 1.0f, ah = ay2 - ay1 + 1.0f;
        float cx = ax1 + 0.5f * aw, cy = ay1 + 0.5f * ah;
        dw = fminf(dw, CLIPV); dh = fminf(dh, CLIPV);
        float pcx = dx * aw + cx, pcy = dy * ah + cy;
        float pw = expf(dw) * aw, ph = expf(dh) * ah;
        float x1 = pcx - 0.5f * pw, y1 = pcy - 0.5f * ph;
        float x2 = pcx + 0.5f * pw - 1.0f, y2 = pcy + 0.5f * ph - 1.0f;
        x1 = fminf(fmaxf(x1, 0.0f), imw - 1.0f);
        y1 = fminf(fmaxf(y1, 0.0f), imh - 1.0f);
        x2 = fminf(fmaxf(x2, 0.0f), imw - 1.0f);
        y2 = fminf(fmaxf(y2, 0.0f), imh - 1.0f);
        bool valid = ((x2 - x1 + 1.0f) >= 0.0f) && ((y2 - y1 + 1.0f) >= 0.0f);
        boxes_s[img * ROWS + t] = make_float4(x1, y1, x2, y2);
        scores_s[img * ROWS + t] = sc;
        if (!valid) atomicOr(&rminit[img * RWORDS + (t >> 5)], 1u << (t & 31));
    }
}

// ---- build upper-triangle IoU>thresh bitmask rows ----
// One wave per row-slice: lanes cover 64 consecutive j (conflict-free LDS reads),
// mask via __ballot, one uint64 store per 64-j block.
__global__ __launch_bounds__(1024) void k_mask(const float4* __restrict__ boxes_s,
                                               uint32_t* __restrict__ mask){
    int img = blockIdx.x >> 4;                 // 16 blocks per image
    int rc  = blockIdx.x & 15;
    int tid = threadIdx.x;
    int lane = tid & 63;
    int wv = tid >> 6;                         // 16 waves per block
    int gw = rc * 16 + wv;                     // 0..255 wave slot within image
    __shared__ float4 B[PRE_K];
    __shared__ float  AR[PRE_K];
    const float4* bp = boxes_s + img * ROWS;
    for (int t = tid; t < PRE_K; t += 1024){
        float4 b = bp[t]; B[t] = b;
        AR[t] = (b.z - b.x + 1.0f) * (b.w - b.y + 1.0f);
    }
    __syncthreads();
    uint32_t* M = mask + (size_t)img * ROWS * RWORDS;
    for (int i = gw; i < PRE_K; i += 256){
        float4 bi = B[i];                      // same address across wave: broadcast
        float ai = AR[i];
        unsigned long long* Mrow = (unsigned long long*)(M + (size_t)i * RWORDS);
        for (int jb = (i >> 6); jb < 32; ++jb){
            int j = (jb << 6) + lane;
            bool pred = false;
            if (j > i && j < PRE_K){
                float4 bj = B[j];
                float xx1 = fmaxf(bi.x, bj.x), yy1 = fmaxf(bi.y, bj.y);
                float xx2 = fminf(bi.z, bj.z), yy2 = fminf(bi.w, bj.w);
                float iw = fmaxf(xx2 - xx1 + 1.0f, 0.0f);
                float ih = fmaxf(yy2 - yy1 + 1.0f, 0.0f);
                float inter = iw * ih;
                pred = inter > NMS_TH * (ai + AR[j] - inter);
            }
            unsigned long long bm = __ballot(pred);
            if (lane == 0) Mrow[jb] = bm;
        }
    }
}

// ---- serial greedy NMS scan (1 wave per image) + compaction of kept list ----
__global__ __launch_bounds__(64) void k_scan(const uint32_t* __restrict__ mask,
                                             const uint32_t* __restrict__ rminit,
                                             uint32_t* __restrict__ sel){
    int img = blockIdx.x; int lane = threadIdx.x;
    const uint32_t* M = mask + (size_t)img * ROWS * RWORDS;
    uint32_t rm = rminit[img * RWORDS + lane];   // invalid boxes start removed
    uint32_t b0 = M[0 * 64 + lane], b1 = M[1 * 64 + lane];
    uint32_t b2 = M[2 * 64 + lane], b3 = M[3 * 64 + lane];
#define STEP(I, BUF) { int w_ = (I) >> 5; uint32_t wd_ = __shfl(rm, w_);            \
        if (!((wd_ >> ((I) & 31)) & 1u) && lane >= w_) rm |= BUF;                    \
        BUF = M[((I) + 4) * 64 + lane]; }
    for (int i = 0; i < PRE_K; i += 4){
        STEP(i, b0); STEP(i + 1, b1); STEP(i + 2, b2); STEP(i + 3, b3);
    }
#undef STEP
    // kept = ~removed within [0, PRE_K)
    uint32_t inr = (lane < 62) ? 0xFFFFFFFFu : (lane == 62 ? 0x0000FFFFu : 0u);
    uint32_t kw = (~rm) & inr;
    uint32_t sw = rm & inr;
    uint32_t kc = __popc(kw);
    uint32_t x = kc;
    for (int d = 1; d < 64; d <<= 1){ uint32_t y = __shfl_up(x, d); if (lane >= d) x += y; }
    uint32_t kexcl = x - kc;
    uint32_t ktot = __shfl(x, 63);
    uint32_t* S = sel + img * 1024;
    uint32_t m = kw; uint32_t r = 0;
    while (m){
        int b = __ffs(m) - 1;
        uint32_t slot = kexcl + r;
        if (slot < POST_K) S[slot] = (uint32_t)(lane * 32 + b) | 0x80000000u;
        m &= m - 1; ++r;
    }
    if (ktot < POST_K){   // pad with suppressed positions in index order, score NEG
        uint32_t sc2 = __popc(sw);
        uint32_t x2 = sc2;
        for (int d = 1; d < 64; d <<= 1){ uint32_t y = __shfl_up(x2, d); if (lane >= d) x2 += y; }
        uint32_t sexcl = x2 - sc2;
        uint32_t m2 = sw; uint32_t r2 = 0;
        while (m2){
            int b = __ffs(m2) - 1;
            uint32_t slot = ktot + sexcl + r2;
            if (slot >= ktot && slot < POST_K) S[slot] = (uint32_t)(lane * 32 + b);
            m2 &= m2 - 1; ++r2;
        }
    }
}

// ---- write [N, 1000, 5] output ----
__global__ void k_out(const uint32_t* __restrict__ sel, const float4* __restrict__ boxes_s,
                      const float* __restrict__ scores_s, float* __restrict__ out){
    int t = blockIdx.x * blockDim.x + threadIdx.x;
    if (t >= NIMG * POST_K) return;
    int img = t / POST_K, s = t - img * POST_K;
    uint32_t v = sel[img * 1024 + s];
    uint32_t pos = v & 0x7FFFFFFFu;
    bool kept = (v >> 31) != 0;
    float4 b = boxes_s[img * ROWS + pos];
    float sc = kept ? scores_s[img * ROWS + pos] : NEGV;
    float* o = out + (size_t)t * 5;
    o[0] = b.x; o[1] = b.y; o[2] = b.z; o[3] = b.w; o[4] = sc;
}

extern "C" void kernel_launch(void* const* d_in, const int* in_sizes, int n_in,
                              void* d_out, int out_size, void* d_ws, size_t ws_size,
                              hipStream_t stream) {
    const float* anchors = (const float*)d_in[0];
    const float* obj     = (const float*)d_in[1];
    const float* breg    = (const float*)d_in[2];
    const int*   pimh    = (const int*)d_in[3];
    const int*   pimw    = (const int*)d_in[4];
    float* out = (float*)d_out;
    uint8_t* ws = (uint8_t*)d_ws;

    uint32_t*           hist     = (uint32_t*)(ws + WS_HIST);
    uint32_t*           cut      = (uint32_t*)(ws + WS_CUT);
    uint32_t*           cnt      = (uint32_t*)(ws + WS_CNT);
    unsigned long long* cand     = (unsigned long long*)(ws + WS_CAND);
    float4*             boxes_s  = (float4*)(ws + WS_BOX);
    float*              scores_s = (float*)(ws + WS_SCO);
    uint32_t*           rminit   = (uint32_t*)(ws + WS_RMI);
    uint32_t*           sel      = (uint32_t*)(ws + WS_SEL);
    uint32_t*           mask     = (uint32_t*)(ws + WS_MASK);

    k_zero<<<1024, 256, 0, stream>>>((uint32_t*)ws);
    k_hist<<<2048, 256, 0, stream>>>(obj, hist);
    k_binsel<<<NIMG, 1024, 0, stream>>>(hist, cut);
    k_compact<<<NIMG * CBLOCKS, 256, 0, stream>>>(obj, cut, cnt, cand);
    k_sortdecode<<<NIMG, 1024, 0, stream>>>(cand, cnt, anchors, breg, pimh, pimw,
                                            boxes_s, scores_s, rminit);
    k_mask<<<NIMG * 16, 1024, 0, stream>>>(boxes_s, mask);
    k_scan<<<NIMG, 64, 0, stream>>>(mask, rminit, sel);
    k_out<<<(NIMG * POST_K + 255) / 256, 256, 0, stream>>>(sel, boxes_s, scores_s, out);
}

// Round 4
// 299.376 us; speedup vs baseline: 4.1587x; 1.8120x over previous
//
#include <hip/hip_runtime.h>
#include <stdint.h>

// ---- problem constants (from setup_inputs) ----
#define NIMG 16
#define AANCH 3
#define HH 256
#define WW 336
#define HWP (HH*WW)            // 86016
#define NUM (AANCH*HWP)        // 258048 anchors per image
#define TOTAL (NIMG*NUM)       // 4128768
#define PRE_K 2000
#define POST_K 1000
#define NMS_TH 0.7f
#define NEGV -1e30f
#define CAND_CAP 4096
#define ROWS 2048              // padded row count for top-2000 arrays
#define RWORDS 64              // 32-bit mask words per NMS row (64*32 = 2048 bits)
#define CHUNK 2048             // elements per k_compact block
#define CBLOCKS (NUM / CHUNK)  // 126 blocks per image
#define HPARTS 16              // histogram partials per image
#define HBINS 4096             // 12-bit key prefix bins
#define HCHUNK (NUM / HPARTS)  // 16128 elements per hist block

// ---- workspace layout (bytes) ----
#define WS_HIST 0u             // 16 * 16 * 4096 * 4  = 4194304 (partial histograms)
#define WS_CUT  4194304u       // 16 * 4  (pad 256)
#define WS_CNT  4194560u       // 16 * 4  (pad 256)
#define WS_CAND 4194816u       // 16 * 4096 * 8       = 524288
#define WS_BOX  4719104u       // 16 * 2048 * 16      = 524288
#define WS_SCO  5243392u       // 16 * 2048 * 4       = 131072
#define WS_RMI  5374464u       // 16 * 64 * 4         = 4096
#define WS_SEL  5378560u       // 16 * 1024 * 4       = 65536
#define WS_MASK 5444096u       // 16 * 2048 * 64 * 4  = 8388608
// total ~13.8 MB

// monotonic float -> uint key (descending float == descending key)
__device__ __forceinline__ uint32_t fkey(float f){
    uint32_t b = __float_as_uint(f);
    return (b & 0x80000000u) ? ~b : (b | 0x80000000u);
}
__device__ __forceinline__ float keyf(uint32_t k){
    uint32_t b = (k & 0x80000000u) ? (k & 0x7FFFFFFFu) : ~k;
    return __uint_as_float(b);
}

// ---- per-block private LDS histogram -> global partials (no global atomics) ----
// Also zeroes cnt + rminit (block 0) since the old k_zero is gone.
__global__ __launch_bounds__(1024) void k_hist(const float* __restrict__ obj,
                                               uint32_t* __restrict__ part,
                                               uint32_t* __restrict__ cnt,
                                               uint32_t* __restrict__ rminit){
    int img = blockIdx.x >> 4;
    int blk = blockIdx.x & 15;
    int tid = threadIdx.x;
    if (blockIdx.x == 0){
        for (int i = tid; i < NIMG + NIMG * RWORDS; i += 1024){
            if (i < NIMG) cnt[i] = 0u;
            else          rminit[i - NIMG] = 0u;
        }
    }
    __shared__ uint32_t h[HBINS];
    #pragma unroll
    for (int i = 0; i < HBINS / 1024; ++i) h[tid + i * 1024] = 0u;
    __syncthreads();
    const float* base = obj + (size_t)img * NUM + (size_t)blk * HCHUNK;
    for (int e = tid * 4; e < HCHUNK; e += 4096){
        float4 v = *(const float4*)(base + e);
        atomicAdd(&h[fkey(v.x) >> 20], 1u);
        atomicAdd(&h[fkey(v.y) >> 20], 1u);
        atomicAdd(&h[fkey(v.z) >> 20], 1u);
        atomicAdd(&h[fkey(v.w) >> 20], 1u);
    }
    __syncthreads();
    uint32_t* p = part + ((size_t)blockIdx.x) * HBINS;
    #pragma unroll
    for (int i = 0; i < HBINS / 1024; ++i) p[tid + i * 1024] = h[tid + i * 1024];
}

// ---- merge partials, find the bin where top-count crosses PRE_K ----
__global__ __launch_bounds__(1024) void k_binsel(const uint32_t* __restrict__ part,
                                                 uint32_t* __restrict__ cut){
    int img = blockIdx.x, tid = threadIdx.x;
    const uint32_t* pb = part + (size_t)img * HPARTS * HBINS;
    int bin0 = HBINS - 4 * (tid + 1);           // tid=0 covers the top 4 bins
    uint32_t c0 = 0, c1 = 0, c2 = 0, c3 = 0;
    for (int k = 0; k < HPARTS; ++k){
        const uint4 v = *(const uint4*)(pb + (size_t)k * HBINS + bin0);
        c0 += v.x; c1 += v.y; c2 += v.z; c3 += v.w;
    }
    uint32_t s = c0 + c1 + c2 + c3;
    __shared__ uint32_t ss[1024];
    uint32_t x = s;
    ss[tid] = x; __syncthreads();
    for (int d = 1; d < 1024; d <<= 1){
        uint32_t y = (tid >= d) ? ss[tid - d] : 0u;
        __syncthreads();
        x += y; ss[tid] = x;
        __syncthreads();
    }
    uint32_t incl = x, excl = x - s;
    if (excl < PRE_K && incl >= PRE_K){
        uint32_t c = excl;
        uint32_t cc[4] = {c0, c1, c2, c3};
        for (int j = 3; j >= 0; --j){            // walk bins descending by value
            c += cc[j];
            if (c >= PRE_K){ cut[img] = ((uint32_t)(bin0 + j)) << 20; break; }
        }
    }
}

// ---- compact candidates (key >= cutoff), block-aggregated atomics ----
__global__ __launch_bounds__(256) void k_compact(const float* __restrict__ obj,
                                                 const uint32_t* __restrict__ cut,
                                                 uint32_t* __restrict__ cnt,
                                                 unsigned long long* __restrict__ cand){
    int img   = blockIdx.x / CBLOCKS;
    int chunk = blockIdx.x - img * CBLOCKS;
    int base  = img * NUM + chunk * CHUNK;     // flat element base
    __shared__ uint32_t lcnt;
    __shared__ uint32_t gbase;
    __shared__ unsigned long long lbuf[CHUNK];
    if (threadIdx.x == 0) lcnt = 0u;
    __syncthreads();
    uint32_t cutv = cut[img];
    #pragma unroll
    for (int it = 0; it < 2; ++it){
        int e = it * 1024 + (int)threadIdx.x * 4;   // element offset within chunk
        float4 v = *(const float4*)(obj + base + e);
        float vv[4] = {v.x, v.y, v.z, v.w};
        #pragma unroll
        for (int q = 0; q < 4; ++q){
            uint32_t k = fkey(vv[q]);
            if (k >= cutv){
                int r = chunk * CHUNK + e + q;       // index within image (a,h,w flat)
                int a = r / HWP, hw = r - a * HWP;
                uint32_t f = (uint32_t)(hw * AANCH + a);  // permute_and_flatten index
                uint32_t p = atomicAdd(&lcnt, 1u);        // LDS atomic: fast
                lbuf[p] = ((unsigned long long)k << 32) | (uint32_t)(~f);
            }
        }
    }
    __syncthreads();
    if (threadIdx.x == 0)
        gbase = (lcnt > 0u) ? atomicAdd(&cnt[img], lcnt) : 0u;  // ONE global atomic/block
    __syncthreads();
    uint32_t n = lcnt, gb = gbase;
    for (uint32_t t = threadIdx.x; t < n; t += 256u){
        uint32_t pos = gb + t;
        if (pos < CAND_CAP) cand[img * CAND_CAP + pos] = lbuf[t];
    }
}

// ---- bitonic sort candidates desc, take top-2000, gather+decode+clip ----
__global__ __launch_bounds__(1024) void k_sortdecode(
        const unsigned long long* __restrict__ cand, const uint32_t* __restrict__ cnt,
        const float* __restrict__ anchors, const float* __restrict__ breg,
        const int* __restrict__ pimh, const int* __restrict__ pimw,
        float4* __restrict__ boxes_s, float* __restrict__ scores_s,
        uint32_t* __restrict__ rminit){
    int img = blockIdx.x, tid = threadIdx.x;
    __shared__ unsigned long long sd[CAND_CAP];
    uint32_t cl = min(cnt[img], (uint32_t)CAND_CAP);
    for (int t = tid; t < CAND_CAP; t += 1024)
        sd[t] = (t < (int)cl) ? cand[img * CAND_CAP + t] : 0ull;
    __syncthreads();
    for (uint32_t k = 2; k <= CAND_CAP; k <<= 1){
        for (uint32_t j = k >> 1; j > 0; j >>= 1){
            for (int t = tid; t < CAND_CAP; t += 1024){
                int ixj = t ^ (int)j;
                if (ixj > t){
                    unsigned long long a = sd[t], b = sd[ixj];
                    bool up = ((t & k) == 0);   // descending overall
                    if (up ? (a < b) : (a > b)){ sd[t] = b; sd[ixj] = a; }
                }
            }
            __syncthreads();
        }
    }
    float imw = (float)(*pimw), imh = (float)(*pimh);
    const float CLIPV = 4.135166556742356f;     // log(1000/16)
    for (int t = tid; t < PRE_K; t += 1024){
        unsigned long long comp = sd[t];
        uint32_t key = (uint32_t)(comp >> 32);
        uint32_t f = ~(uint32_t)comp;
        float logit = keyf(key);
        float sc = 1.0f / (1.0f + expf(-logit));
        const float* an = anchors + ((size_t)img * NUM + f) * 4;
        float ax1 = an[0], ay1 = an[1], ax2 = an[2], ay2 = an[3];
        int a = (int)(f % AANCH); int hw = (int)(f / AANCH);
        int h = hw / WW; int w = hw - h * WW;
        size_t bbase = ((size_t)img * 12 + a * 4) * HWP + (size_t)h * WW + w;
        float dx = breg[bbase], dy = breg[bbase + HWP];
        float dw = breg[bbase + 2 * (size_t)HWP], dh = breg[bbase + 3 * (size_t)HWP];
        float aw = ax2 - ax1 + 1.0f, ah = ay2 - ay1 + 1.0f;
        float cx = ax1 + 0.5f * aw, cy = ay1 + 0.5f * ah;
        dw = fminf(dw, CLIPV); dh = fminf(dh, CLIPV);
        float pcx = dx * aw + cx, pcy = dy * ah + cy;
        float pw = expf(dw) * aw, ph = expf(dh) * ah;
        float x1 = pcx - 0.5f * pw, y1 = pcy - 0.5f * ph;
        float x2 = pcx + 0.5f * pw - 1.0f, y2 = pcy + 0.5f * ph - 1.0f;
        x1 = fminf(fmaxf(x1, 0.0f), imw - 1.0f);
        y1 = fminf(fmaxf(y1, 0.0f), imh - 1.0f);
        x2 = fminf(fmaxf(x2, 0.0f), imw - 1.0f);
        y2 = fminf(fmaxf(y2, 0.0f), imh - 1.0f);
        bool valid = ((x2 - x1 + 1.0f) >= 0.0f) && ((y2 - y1 + 1.0f) >= 0.0f);
        boxes_s[img * ROWS + t] = make_float4(x1, y1, x2, y2);
        scores_s[img * ROWS + t] = sc;
        if (!valid) atomicOr(&rminit[img * RWORDS + (t >> 5)], 1u << (t & 31));
    }
}

// ---- build upper-triangle IoU>thresh bitmask rows ----
// One wave per row-slice: lanes cover 64 consecutive j (conflict-free LDS reads),
// mask via __ballot, one uint64 store per 64-j block.
__global__ __launch_bounds__(1024) void k_mask(const float4* __restrict__ boxes_s,
                                               uint32_t* __restrict__ mask){
    int img = blockIdx.x >> 4;                 // 16 blocks per image
    int rc  = blockIdx.x & 15;
    int tid = threadIdx.x;
    int lane = tid & 63;
    int wv = tid >> 6;                         // 16 waves per block
    int gw = rc * 16 + wv;                     // 0..255 wave slot within image
    __shared__ float4 B[PRE_K];
    __shared__ float  AR[PRE_K];
    const float4* bp = boxes_s + img * ROWS;
    for (int t = tid; t < PRE_K; t += 1024){
        float4 b = bp[t]; B[t] = b;
        AR[t] = (b.z - b.x + 1.0f) * (b.w - b.y + 1.0f);
    }
    __syncthreads();
    uint32_t* M = mask + (size_t)img * ROWS * RWORDS;
    for (int i = gw; i < PRE_K; i += 256){
        float4 bi = B[i];                      // same address across wave: broadcast
        float ai = AR[i];
        unsigned long long* Mrow = (unsigned long long*)(M + (size_t)i * RWORDS);
        for (int jb = (i >> 6); jb < 32; ++jb){
            int j = (jb << 6) + lane;
            bool pred = false;
            if (j > i && j < PRE_K){
                float4 bj = B[j];
                float xx1 = fmaxf(bi.x, bj.x), yy1 = fmaxf(bi.y, bj.y);
                float xx2 = fminf(bi.z, bj.z), yy2 = fminf(bi.w, bj.w);
                float iw = fmaxf(xx2 - xx1 + 1.0f, 0.0f);
                float ih = fmaxf(yy2 - yy1 + 1.0f, 0.0f);
                float inter = iw * ih;
                pred = inter > NMS_TH * (ai + AR[j] - inter);
            }
            unsigned long long bm = __ballot(pred);
            if (lane == 0) Mrow[jb] = bm;
        }
    }
}

// ---- serial greedy NMS scan (1 wave per image) + compaction of kept list ----
__global__ __launch_bounds__(64) void k_scan(const uint32_t* __restrict__ mask,
                                             const uint32_t* __restrict__ rminit,
                                             uint32_t* __restrict__ sel){
    int img = blockIdx.x; int lane = threadIdx.x;
    const uint32_t* M = mask + (size_t)img * ROWS * RWORDS;
    uint32_t rm = rminit[img * RWORDS + lane];   // invalid boxes start removed
    uint32_t b0 = M[0 * 64 + lane], b1 = M[1 * 64 + lane];
    uint32_t b2 = M[2 * 64 + lane], b3 = M[3 * 64 + lane];
#define STEP(I, BUF) { int w_ = (I) >> 5; uint32_t wd_ = __shfl(rm, w_);            \
        if (!((wd_ >> ((I) & 31)) & 1u) && lane >= w_) rm |= BUF;                    \
        BUF = M[((I) + 4) * 64 + lane]; }
    for (int i = 0; i < PRE_K; i += 4){
        STEP(i, b0); STEP(i + 1, b1); STEP(i + 2, b2); STEP(i + 3, b3);
    }
#undef STEP
    // kept = ~removed within [0, PRE_K)
    uint32_t inr = (lane < 62) ? 0xFFFFFFFFu : (lane == 62 ? 0x0000FFFFu : 0u);
    uint32_t kw = (~rm) & inr;
    uint32_t sw = rm & inr;
    uint32_t kc = __popc(kw);
    uint32_t x = kc;
    for (int d = 1; d < 64; d <<= 1){ uint32_t y = __shfl_up(x, d); if (lane >= d) x += y; }
    uint32_t kexcl = x - kc;
    uint32_t ktot = __shfl(x, 63);
    uint32_t* S = sel + img * 1024;
    uint32_t m = kw; uint32_t r = 0;
    while (m){
        int b = __ffs(m) - 1;
        uint32_t slot = kexcl + r;
        if (slot < POST_K) S[slot] = (uint32_t)(lane * 32 + b) | 0x80000000u;
        m &= m - 1; ++r;
    }
    if (ktot < POST_K){   // pad with suppressed positions in index order, score NEG
        uint32_t sc2 = __popc(sw);
        uint32_t x2 = sc2;
        for (int d = 1; d < 64; d <<= 1){ uint32_t y = __shfl_up(x2, d); if (lane >= d) x2 += y; }
        uint32_t sexcl = x2 - sc2;
        uint32_t m2 = sw; uint32_t r2 = 0;
        while (m2){
            int b = __ffs(m2) - 1;
            uint32_t slot = ktot + sexcl + r2;
            if (slot >= ktot && slot < POST_K) S[slot] = (uint32_t)(lane * 32 + b);
            m2 &= m2 - 1; ++r2;
        }
    }
}

// ---- write [N, 1000, 5] output ----
__global__ void k_out(const uint32_t* __restrict__ sel, const float4* __restrict__ boxes_s,
                      const float* __restrict__ scores_s, float* __restrict__ out){
    int t = blockIdx.x * blockDim.x + threadIdx.x;
    if (t >= NIMG * POST_K) return;
    int img = t / POST_K, s = t - img * POST_K;
    uint32_t v = sel[img * 1024 + s];
    uint32_t pos = v & 0x7FFFFFFFu;
    bool kept = (v >> 31) != 0;
    float4 b = boxes_s[img * ROWS + pos];
    float sc = kept ? scores_s[img * ROWS + pos] : NEGV;
    float* o = out + (size_t)t * 5;
    o[0] = b.x; o[1] = b.y; o[2] = b.z; o[3] = b.w; o[4] = sc;
}

extern "C" void kernel_launch(void* const* d_in, const int* in_sizes, int n_in,
                              void* d_out, int out_size, void* d_ws, size_t ws_size,
                              hipStream_t stream) {
    const float* anchors = (const float*)d_in[0];
    const float* obj     = (const float*)d_in[1];
    const float* breg    = (const float*)d_in[2];
    const int*   pimh    = (const int*)d_in[3];
    const int*   pimw    = (const int*)d_in[4];
    float* out = (float*)d_out;
    uint8_t* ws = (uint8_t*)d_ws;

    uint32_t*           part     = (uint32_t*)(ws + WS_HIST);
    uint32_t*           cut      = (uint32_t*)(ws + WS_CUT);
    uint32_t*           cnt      = (uint32_t*)(ws + WS_CNT);
    unsigned long long* cand     = (unsigned long long*)(ws + WS_CAND);
    float4*             boxes_s  = (float4*)(ws + WS_BOX);
    float*              scores_s = (float*)(ws + WS_SCO);
    uint32_t*           rminit   = (uint32_t*)(ws + WS_RMI);
    uint32_t*           sel      = (uint32_t*)(ws + WS_SEL);
    uint32_t*           mask     = (uint32_t*)(ws + WS_MASK);

    k_hist<<<NIMG * HPARTS, 1024, 0, stream>>>(obj, part, cnt, rminit);
    k_binsel<<<NIMG, 1024, 0, stream>>>(part, cut);
    k_compact<<<NIMG * CBLOCKS, 256, 0, stream>>>(obj, cut, cnt, cand);
    k_sortdecode<<<NIMG, 1024, 0, stream>>>(cand, cnt, anchors, breg, pimh, pimw,
                                            boxes_s, scores_s, rminit);
    k_mask<<<NIMG * 16, 1024, 0, stream>>>(boxes_s, mask);
    k_scan<<<NIMG, 64, 0, stream>>>(mask, rminit, sel);
    k_out<<<(NIMG * POST_K + 255) / 256, 256, 0, stream>>>(sel, boxes_s, scores_s, out);
}

// Round 5
// 195.695 us; speedup vs baseline: 6.3619x; 1.5298x over previous
//
#include <hip/hip_runtime.h>
#include <stdint.h>

// ---- problem constants (from setup_inputs) ----
#define NIMG 16
#define AANCH 3
#define HH 256
#define WW 336
#define HWP (HH*WW)            // 86016
#define NUM (AANCH*HWP)        // 258048 anchors per image
#define TOTAL (NIMG*NUM)       // 4128768
#define PRE_K 2000
#define POST_K 1000
#define NMS_TH 0.7f
#define NEGV -1e30f
#define CAND_CAP 4096
#define ROWS 2048              // padded row count for top-2000 arrays
#define RWORDS 64              // 32-bit mask words per NMS row (64*32 = 2048 bits)
#define CHUNK 2048             // elements per k_compact block
#define CBLOCKS (NUM / CHUNK)  // 126 blocks per image
#define HPARTS 16              // histogram partials per image
#define HBINS 4096             // 12-bit key prefix bins
#define HCHUNK (NUM / HPARTS)  // 16128 elements per hist block

// ---- workspace layout (bytes) ----
#define WS_HIST 0u             // 16 * 16 * 4096 * 4  = 4194304 (partial histograms)
                               // colT (16*32*64*8 = 262144 B) ALIASES this region
                               // (hist is dead after k_binsel; k_diag runs later)
#define WS_CUT  4194304u       // 16 * 4  (pad 256)
#define WS_CNT  4194560u       // 16 * 4  (pad 256)
#define WS_CAND 4194816u       // 16 * 4096 * 8       = 524288
#define WS_BOX  4719104u       // 16 * 2048 * 16      = 524288
#define WS_SCO  5243392u       // 16 * 2048 * 4       = 131072
#define WS_RMI  5374464u       // 16 * 64 * 4         = 4096
#define WS_SEL  5378560u       // 16 * 1024 * 4       = 65536
#define WS_MASK 5444096u       // 16 * 2048 * 64 * 4  = 8388608
// total ~13.8 MB

// monotonic float -> uint key (descending float == descending key)
__device__ __forceinline__ uint32_t fkey(float f){
    uint32_t b = __float_as_uint(f);
    return (b & 0x80000000u) ? ~b : (b | 0x80000000u);
}
__device__ __forceinline__ float keyf(uint32_t k){
    uint32_t b = (k & 0x80000000u) ? (k & 0x7FFFFFFFu) : ~k;
    return __uint_as_float(b);
}

// ---- per-block private LDS histogram -> global partials (no global atomics) ----
// Also zeroes cnt + rminit (block 0) since the old k_zero is gone.
__global__ __launch_bounds__(1024) void k_hist(const float* __restrict__ obj,
                                               uint32_t* __restrict__ part,
                                               uint32_t* __restrict__ cnt,
                                               uint32_t* __restrict__ rminit){
    int img = blockIdx.x >> 4;
    int blk = blockIdx.x & 15;
    int tid = threadIdx.x;
    if (blockIdx.x == 0){
        for (int i = tid; i < NIMG + NIMG * RWORDS; i += 1024){
            if (i < NIMG) cnt[i] = 0u;
            else          rminit[i - NIMG] = 0u;
        }
    }
    __shared__ uint32_t h[HBINS];
    #pragma unroll
    for (int i = 0; i < HBINS / 1024; ++i) h[tid + i * 1024] = 0u;
    __syncthreads();
    const float* base = obj + (size_t)img * NUM + (size_t)blk * HCHUNK;
    for (int e = tid * 4; e < HCHUNK; e += 4096){
        float4 v = *(const float4*)(base + e);
        atomicAdd(&h[fkey(v.x) >> 20], 1u);
        atomicAdd(&h[fkey(v.y) >> 20], 1u);
        atomicAdd(&h[fkey(v.z) >> 20], 1u);
        atomicAdd(&h[fkey(v.w) >> 20], 1u);
    }
    __syncthreads();
    uint32_t* p = part + ((size_t)blockIdx.x) * HBINS;
    #pragma unroll
    for (int i = 0; i < HBINS / 1024; ++i) p[tid + i * 1024] = h[tid + i * 1024];
}

// ---- merge partials, find the bin where top-count crosses PRE_K ----
__global__ __launch_bounds__(1024) void k_binsel(const uint32_t* __restrict__ part,
                                                 uint32_t* __restrict__ cut){
    int img = blockIdx.x, tid = threadIdx.x;
    const uint32_t* pb = part + (size_t)img * HPARTS * HBINS;
    int bin0 = HBINS - 4 * (tid + 1);           // tid=0 covers the top 4 bins
    uint32_t c0 = 0, c1 = 0, c2 = 0, c3 = 0;
    for (int k = 0; k < HPARTS; ++k){
        const uint4 v = *(const uint4*)(pb + (size_t)k * HBINS + bin0);
        c0 += v.x; c1 += v.y; c2 += v.z; c3 += v.w;
    }
    uint32_t s = c0 + c1 + c2 + c3;
    __shared__ uint32_t ss[1024];
    uint32_t x = s;
    ss[tid] = x; __syncthreads();
    for (int d = 1; d < 1024; d <<= 1){
        uint32_t y = (tid >= d) ? ss[tid - d] : 0u;
        __syncthreads();
        x += y; ss[tid] = x;
        __syncthreads();
    }
    uint32_t incl = x, excl = x - s;
    if (excl < PRE_K && incl >= PRE_K){
        uint32_t c = excl;
        uint32_t cc[4] = {c0, c1, c2, c3};
        for (int j = 3; j >= 0; --j){            // walk bins descending by value
            c += cc[j];
            if (c >= PRE_K){ cut[img] = ((uint32_t)(bin0 + j)) << 20; break; }
        }
    }
}

// ---- compact candidates (key >= cutoff), block-aggregated atomics ----
__global__ __launch_bounds__(256) void k_compact(const float* __restrict__ obj,
                                                 const uint32_t* __restrict__ cut,
                                                 uint32_t* __restrict__ cnt,
                                                 unsigned long long* __restrict__ cand){
    int img   = blockIdx.x / CBLOCKS;
    int chunk = blockIdx.x - img * CBLOCKS;
    int base  = img * NUM + chunk * CHUNK;     // flat element base
    __shared__ uint32_t lcnt;
    __shared__ uint32_t gbase;
    __shared__ unsigned long long lbuf[CHUNK];
    if (threadIdx.x == 0) lcnt = 0u;
    __syncthreads();
    uint32_t cutv = cut[img];
    #pragma unroll
    for (int it = 0; it < 2; ++it){
        int e = it * 1024 + (int)threadIdx.x * 4;   // element offset within chunk
        float4 v = *(const float4*)(obj + base + e);
        float vv[4] = {v.x, v.y, v.z, v.w};
        #pragma unroll
        for (int q = 0; q < 4; ++q){
            uint32_t k = fkey(vv[q]);
            if (k >= cutv){
                int r = chunk * CHUNK + e + q;       // index within image (a,h,w flat)
                int a = r / HWP, hw = r - a * HWP;
                uint32_t f = (uint32_t)(hw * AANCH + a);  // permute_and_flatten index
                uint32_t p = atomicAdd(&lcnt, 1u);        // LDS atomic: fast
                lbuf[p] = ((unsigned long long)k << 32) | (uint32_t)(~f);
            }
        }
    }
    __syncthreads();
    if (threadIdx.x == 0)
        gbase = (lcnt > 0u) ? atomicAdd(&cnt[img], lcnt) : 0u;  // ONE global atomic/block
    __syncthreads();
    uint32_t n = lcnt, gb = gbase;
    for (uint32_t t = threadIdx.x; t < n; t += 256u){
        uint32_t pos = gb + t;
        if (pos < CAND_CAP) cand[img * CAND_CAP + pos] = lbuf[t];
    }
}

// ---- bitonic sort candidates desc, take top-2000, gather+decode+clip ----
__global__ __launch_bounds__(1024) void k_sortdecode(
        const unsigned long long* __restrict__ cand, const uint32_t* __restrict__ cnt,
        const float* __restrict__ anchors, const float* __restrict__ breg,
        const int* __restrict__ pimh, const int* __restrict__ pimw,
        float4* __restrict__ boxes_s, float* __restrict__ scores_s,
        uint32_t* __restrict__ rminit){
    int img = blockIdx.x, tid = threadIdx.x;
    __shared__ unsigned long long sd[CAND_CAP];
    uint32_t cl = min(cnt[img], (uint32_t)CAND_CAP);
    for (int t = tid; t < CAND_CAP; t += 1024)
        sd[t] = (t < (int)cl) ? cand[img * CAND_CAP + t] : 0ull;
    __syncthreads();
    for (uint32_t k = 2; k <= CAND_CAP; k <<= 1){
        for (uint32_t j = k >> 1; j > 0; j >>= 1){
            for (int t = tid; t < CAND_CAP; t += 1024){
                int ixj = t ^ (int)j;
                if (ixj > t){
                    unsigned long long a = sd[t], b = sd[ixj];
                    bool up = ((t & k) == 0);   // descending overall
                    if (up ? (a < b) : (a > b)){ sd[t] = b; sd[ixj] = a; }
                }
            }
            __syncthreads();
        }
    }
    float imw = (float)(*pimw), imh = (float)(*pimh);
    const float CLIPV = 4.135166556742356f;     // log(1000/16)
    for (int t = tid; t < PRE_K; t += 1024){
        unsigned long long comp = sd[t];
        uint32_t key = (uint32_t)(comp >> 32);
        uint32_t f = ~(uint32_t)comp;
        float logit = keyf(key);
        float sc = 1.0f / (1.0f + expf(-logit));
        const float* an = anchors + ((size_t)img * NUM + f) * 4;
        float ax1 = an[0], ay1 = an[1], ax2 = an[2], ay2 = an[3];
        int a = (int)(f % AANCH); int hw = (int)(f / AANCH);
        int h = hw / WW; int w = hw - h * WW;
        size_t bbase = ((size_t)img * 12 + a * 4) * HWP + (size_t)h * WW + w;
        float dx = breg[bbase], dy = breg[bbase + HWP];
        float dw = breg[bbase + 2 * (size_t)HWP], dh = breg[bbase + 3 * (size_t)HWP];
        float aw = ax2 - ax1 + 1.0f, ah = ay2 - ay1 + 1.0f;
        float cx = ax1 + 0.5f * aw, cy = ay1 + 0.5f * ah;
        dw = fminf(dw, CLIPV); dh = fminf(dh, CLIPV);
        float pcx = dx * aw + cx, pcy = dy * ah + cy;
        float pw = expf(dw) * aw, ph = expf(dh) * ah;
        float x1 = pcx - 0.5f * pw, y1 = pcy - 0.5f * ph;
        float x2 = pcx + 0.5f * pw - 1.0f, y2 = pcy + 0.5f * ph - 1.0f;
        x1 = fminf(fmaxf(x1, 0.0f), imw - 1.0f);
        y1 = fminf(fmaxf(y1, 0.0f), imh - 1.0f);
        x2 = fminf(fmaxf(x2, 0.0f), imw - 1.0f);
        y2 = fminf(fmaxf(y2, 0.0f), imh - 1.0f);
        bool valid = ((x2 - x1 + 1.0f) >= 0.0f) && ((y2 - y1 + 1.0f) >= 0.0f);
        boxes_s[img * ROWS + t] = make_float4(x1, y1, x2, y2);
        scores_s[img * ROWS + t] = sc;
        if (!valid) atomicOr(&rminit[img * RWORDS + (t >> 5)], 1u << (t & 31));
    }
}

// ---- transposed 64x64 diagonal blocks: col_j bit i = (i suppresses j), i<j ----
__global__ __launch_bounds__(64) void k_diag(const float4* __restrict__ boxes_s,
                                             unsigned long long* __restrict__ colT){
    int img = blockIdx.x >> 5;
    int b   = blockIdx.x & 31;
    int j   = threadIdx.x;
    __shared__ float4 B[64];
    __shared__ float  AR[64];
    float4 bj = boxes_s[img * ROWS + b * 64 + j];
    float aj = (bj.z - bj.x + 1.0f) * (bj.w - bj.y + 1.0f);
    B[j] = bj; AR[j] = aj;
    __syncthreads();
    unsigned long long col = 0ull;
    #pragma unroll 8
    for (int i = 0; i < 64; ++i){
        float4 bi = B[i]; float ai = AR[i];
        float xx1 = fmaxf(bi.x, bj.x), yy1 = fmaxf(bi.y, bj.y);
        float xx2 = fminf(bi.z, bj.z), yy2 = fminf(bi.w, bj.w);
        float iw = fmaxf(xx2 - xx1 + 1.0f, 0.0f);
        float ih = fmaxf(yy2 - yy1 + 1.0f, 0.0f);
        float inter = iw * ih;
        bool pred = (i < j) && (inter > NMS_TH * (ai + aj - inter));
        col |= pred ? (1ull << i) : 0ull;
    }
    colT[(size_t)(img * 32 + b) * 64 + j] = col;
}

// ---- build upper-triangle IoU>thresh bitmask rows ----
// One wave per row-slice: lanes cover 64 consecutive j (conflict-free LDS reads),
// mask via __ballot, one uint64 store per 64-j block.
__global__ __launch_bounds__(1024) void k_mask(const float4* __restrict__ boxes_s,
                                               uint32_t* __restrict__ mask){
    int img = blockIdx.x >> 4;                 // 16 blocks per image
    int rc  = blockIdx.x & 15;
    int tid = threadIdx.x;
    int lane = tid & 63;
    int wv = tid >> 6;                         // 16 waves per block
    int gw = rc * 16 + wv;                     // 0..255 wave slot within image
    __shared__ float4 B[PRE_K];
    __shared__ float  AR[PRE_K];
    const float4* bp = boxes_s + img * ROWS;
    for (int t = tid; t < PRE_K; t += 1024){
        float4 b = bp[t]; B[t] = b;
        AR[t] = (b.z - b.x + 1.0f) * (b.w - b.y + 1.0f);
    }
    __syncthreads();
    uint32_t* M = mask + (size_t)img * ROWS * RWORDS;
    for (int i = gw; i < PRE_K; i += 256){
        float4 bi = B[i];                      // same address across wave: broadcast
        float ai = AR[i];
        unsigned long long* Mrow = (unsigned long long*)(M + (size_t)i * RWORDS);
        for (int jb = (i >> 6); jb < 32; ++jb){
            int j = (jb << 6) + lane;
            bool pred = false;
            if (j > i && j < PRE_K){
                float4 bj = B[j];
                float xx1 = fmaxf(bi.x, bj.x), yy1 = fmaxf(bi.y, bj.y);
                float xx2 = fminf(bi.z, bj.z), yy2 = fminf(bi.w, bj.w);
                float iw = fmaxf(xx2 - xx1 + 1.0f, 0.0f);
                float ih = fmaxf(yy2 - yy1 + 1.0f, 0.0f);
                float inter = iw * ih;
                pred = inter > NMS_TH * (ai + AR[j] - inter);
            }
            unsigned long long bm = __ballot(pred);
            if (lane == 0) Mrow[jb] = bm;
        }
    }
}

// ---- blocked greedy NMS scan: 32 phases of {ballot fixed-point + parallel apply} ----
__global__ __launch_bounds__(64) void k_scan(const uint32_t* __restrict__ mask,
                                             const unsigned long long* __restrict__ colT,
                                             const uint32_t* __restrict__ rminit,
                                             uint32_t* __restrict__ sel){
    int img = blockIdx.x; int lane = threadIdx.x;
    const uint32_t* M = mask + (size_t)img * ROWS * RWORDS;
    const unsigned long long* CT = colT + (size_t)img * 32 * 64;
    // initial removed: invalid boxes + padding rows >= PRE_K
    uint32_t rm = rminit[img * RWORDS + lane];
    if (lane == 62) rm |= 0xFFFF0000u;          // boxes 2000..2015
    if (lane == 63) rm  = 0xFFFFFFFFu;          // boxes 2016..2047
    unsigned long long col = CT[lane];          // block 0 columns
    #pragma unroll 1
    for (int b = 0; b < 32; ++b){
        // issue apply loads for this block (independent of resolution result)
        const uint32_t* Mb = M + (size_t)(b * 64) * RWORDS + lane;
        uint32_t mrow[64];
        #pragma unroll
        for (int i = 0; i < 64; ++i) mrow[i] = Mb[(size_t)i * RWORDS];
        // prefetch next block's columns
        unsigned long long coln = (b < 31) ? CT[(size_t)(b + 1) * 64 + lane] : 0ull;
        // incoming removed bits for this block
        uint32_t lo = __shfl(rm, 2 * b), hi = __shfl(rm, 2 * b + 1);
        unsigned long long inc = ((unsigned long long)hi << 32) | (unsigned long long)lo;
        bool alivej = ((inc >> lane) & 1ull) == 0ull;
        unsigned long long keep = ~inc;          // == ballot(alivej)
        #pragma unroll 1
        for (int it = 0; it < 66; ++it){         // converges in <=64 (prefix induction)
            bool ok = alivej && ((col & keep) == 0ull);
            unsigned long long nk = __ballot(ok);
            if (nk == keep) break;
            keep = nk;
        }
        // apply: OR mask rows of kept boxes into distributed removed state
        uint32_t acc = 0u;
        #pragma unroll
        for (int i = 0; i < 64; ++i)
            acc |= (keep & (1ull << i)) ? mrow[i] : 0u;
        rm |= (lane >= 2 * b) ? acc : 0u;        // words below diag are unwritten garbage
        // finalize this block's own removed words
        unsigned long long rmb = ~keep;
        if (lane == 2 * b)     rm = (uint32_t)rmb;
        if (lane == 2 * b + 1) rm = (uint32_t)(rmb >> 32);
        col = coln;
    }
    // kept = ~removed within [0, PRE_K)
    uint32_t inr = (lane < 62) ? 0xFFFFFFFFu : (lane == 62 ? 0x0000FFFFu : 0u);
    uint32_t kw = (~rm) & inr;
    uint32_t sw = rm & inr;
    uint32_t kc = __popc(kw);
    uint32_t x = kc;
    for (int d = 1; d < 64; d <<= 1){ uint32_t y = __shfl_up(x, d); if (lane >= d) x += y; }
    uint32_t kexcl = x - kc;
    uint32_t ktot = __shfl(x, 63);
    uint32_t* S = sel + img * 1024;
    uint32_t m = kw; uint32_t r = 0;
    while (m){
        int b = __ffs(m) - 1;
        uint32_t slot = kexcl + r;
        if (slot < POST_K) S[slot] = (uint32_t)(lane * 32 + b) | 0x80000000u;
        m &= m - 1; ++r;
    }
    if (ktot < POST_K){   // pad with suppressed positions in index order, score NEG
        uint32_t sc2 = __popc(sw);
        uint32_t x2 = sc2;
        for (int d = 1; d < 64; d <<= 1){ uint32_t y = __shfl_up(x2, d); if (lane >= d) x2 += y; }
        uint32_t sexcl = x2 - sc2;
        uint32_t m2 = sw; uint32_t r2 = 0;
        while (m2){
            int b = __ffs(m2) - 1;
            uint32_t slot = ktot + sexcl + r2;
            if (slot >= ktot && slot < POST_K) S[slot] = (uint32_t)(lane * 32 + b);
            m2 &= m2 - 1; ++r2;
        }
    }
}

// ---- write [N, 1000, 5] output ----
__global__ void k_out(const uint32_t* __restrict__ sel, const float4* __restrict__ boxes_s,
                      const float* __restrict__ scores_s, float* __restrict__ out){
    int t = blockIdx.x * blockDim.x + threadIdx.x;
    if (t >= NIMG * POST_K) return;
    int img = t / POST_K, s = t - img * POST_K;
    uint32_t v = sel[img * 1024 + s];
    uint32_t pos = v & 0x7FFFFFFFu;
    bool kept = (v >> 31) != 0;
    float4 b = boxes_s[img * ROWS + pos];
    float sc = kept ? scores_s[img * ROWS + pos] : NEGV;
    float* o = out + (size_t)t * 5;
    o[0] = b.x; o[1] = b.y; o[2] = b.z; o[3] = b.w; o[4] = sc;
}

extern "C" void kernel_launch(void* const* d_in, const int* in_sizes, int n_in,
                              void* d_out, int out_size, void* d_ws, size_t ws_size,
                              hipStream_t stream) {
    const float* anchors = (const float*)d_in[0];
    const float* obj     = (const float*)d_in[1];
    const float* breg    = (const float*)d_in[2];
    const int*   pimh    = (const int*)d_in[3];
    const int*   pimw    = (const int*)d_in[4];
    float* out = (float*)d_out;
    uint8_t* ws = (uint8_t*)d_ws;

    uint32_t*           part     = (uint32_t*)(ws + WS_HIST);
    unsigned long long* colT     = (unsigned long long*)(ws + WS_HIST);  // alias, post-binsel
    uint32_t*           cut      = (uint32_t*)(ws + WS_CUT);
    uint32_t*           cnt      = (uint32_t*)(ws + WS_CNT);
    unsigned long long* cand     = (unsigned long long*)(ws + WS_CAND);
    float4*             boxes_s  = (float4*)(ws + WS_BOX);
    float*              scores_s = (float*)(ws + WS_SCO);
    uint32_t*           rminit   = (uint32_t*)(ws + WS_RMI);
    uint32_t*           sel      = (uint32_t*)(ws + WS_SEL);
    uint32_t*           mask     = (uint32_t*)(ws + WS_MASK);

    k_hist<<<NIMG * HPARTS, 1024, 0, stream>>>(obj, part, cnt, rminit);
    k_binsel<<<NIMG, 1024, 0, stream>>>(part, cut);
    k_compact<<<NIMG * CBLOCKS, 256, 0, stream>>>(obj, cut, cnt, cand);
    k_sortdecode<<<NIMG, 1024, 0, stream>>>(cand, cnt, anchors, breg, pimh, pimw,
                                            boxes_s, scores_s, rminit);
    k_diag<<<NIMG * 32, 64, 0, stream>>>(boxes_s, colT);
    k_mask<<<NIMG * 16, 1024, 0, stream>>>(boxes_s, mask);
    k_scan<<<NIMG, 64, 0, stream>>>(mask, colT, rminit, sel);
    k_out<<<(NIMG * POST_K + 255) / 256, 256, 0, stream>>>(sel, boxes_s, scores_s, out);
}

// Round 6
// 187.795 us; speedup vs baseline: 6.6296x; 1.0421x over previous
//
#include <hip/hip_runtime.h>
#include <stdint.h>

// ---- problem constants (from setup_inputs) ----
#define NIMG 16
#define AANCH 3
#define HH 256
#define WW 336
#define HWP (HH*WW)            // 86016
#define NUM (AANCH*HWP)        // 258048 anchors per image
#define TOTAL (NIMG*NUM)       // 4128768
#define PRE_K 2000
#define POST_K 1000
#define NMS_TH 0.7f
#define NEGV -1e30f
#define CAND_CAP 4096
#define ROWS 2048              // padded row count for top-2000 arrays
#define RWORDS 64              // 32-bit mask words per NMS row (64*32 = 2048 bits)
#define CHUNK 2048             // elements per k_compact block
#define CBLOCKS (NUM / CHUNK)  // 126 blocks per image
#define HPARTS 16              // histogram partials per image
#define HBINS 4096             // 12-bit key prefix bins
#define HCHUNK (NUM / HPARTS)  // 16128 elements per hist block

// ---- workspace layout (bytes) ----
#define WS_HIST 0u             // 16 * 16 * 4096 * 4  = 4194304 (partial histograms)
                               // region is DEAD after k_binsel; aliased below:
#define WS_COLT 0u             //   colT   16*32*64*8 = 262144   (written by k_diag)
#define WS_CBOX 262144u        //   cboxes 16*4096*16 = 1048576  (written by k_compact)
#define WS_CSCO 1310720u       //   cscores 16*4096*4 = 262144   (written by k_compact)
#define WS_CUT  4194304u       // 16 * 4  (pad 256)
#define WS_CNT  4194560u       // 16 * 4  (pad 256)
#define WS_CAND 4194816u       // 16 * 4096 * 8       = 524288
#define WS_BOX  4719104u       // 16 * 2048 * 16      = 524288
#define WS_SCO  5243392u       // 16 * 2048 * 4       = 131072
#define WS_RMI  5374464u       // 16 * 64 * 4         = 4096
#define WS_SEL  5378560u       // 16 * 1024 * 4       = 65536
#define WS_MASK 5444096u       // 16 * 2048 * 64 * 4  = 8388608
// total ~13.8 MB

// monotonic float -> uint key (descending float == descending key)
__device__ __forceinline__ uint32_t fkey(float f){
    uint32_t b = __float_as_uint(f);
    return (b & 0x80000000u) ? ~b : (b | 0x80000000u);
}
__device__ __forceinline__ float keyf(uint32_t k){
    uint32_t b = (k & 0x80000000u) ? (k & 0x7FFFFFFFu) : ~k;
    return __uint_as_float(b);
}

// ---- per-block private LDS histogram -> global partials (no global atomics) ----
// Also zeroes cnt + rminit (block 0) since the old k_zero is gone.
__global__ __launch_bounds__(1024) void k_hist(const float* __restrict__ obj,
                                               uint32_t* __restrict__ part,
                                               uint32_t* __restrict__ cnt,
                                               uint32_t* __restrict__ rminit){
    int img = blockIdx.x >> 4;
    int blk = blockIdx.x & 15;
    int tid = threadIdx.x;
    if (blockIdx.x == 0){
        for (int i = tid; i < NIMG + NIMG * RWORDS; i += 1024){
            if (i < NIMG) cnt[i] = 0u;
            else          rminit[i - NIMG] = 0u;
        }
    }
    __shared__ uint32_t h[HBINS];
    #pragma unroll
    for (int i = 0; i < HBINS / 1024; ++i) h[tid + i * 1024] = 0u;
    __syncthreads();
    const float* base = obj + (size_t)img * NUM + (size_t)blk * HCHUNK;
    for (int e = tid * 4; e < HCHUNK; e += 4096){
        float4 v = *(const float4*)(base + e);
        atomicAdd(&h[fkey(v.x) >> 20], 1u);
        atomicAdd(&h[fkey(v.y) >> 20], 1u);
        atomicAdd(&h[fkey(v.z) >> 20], 1u);
        atomicAdd(&h[fkey(v.w) >> 20], 1u);
    }
    __syncthreads();
    uint32_t* p = part + ((size_t)blockIdx.x) * HBINS;
    #pragma unroll
    for (int i = 0; i < HBINS / 1024; ++i) p[tid + i * 1024] = h[tid + i * 1024];
}

// ---- merge partials, find the bin where top-count crosses PRE_K ----
__global__ __launch_bounds__(1024) void k_binsel(const uint32_t* __restrict__ part,
                                                 uint32_t* __restrict__ cut){
    int img = blockIdx.x, tid = threadIdx.x;
    const uint32_t* pb = part + (size_t)img * HPARTS * HBINS;
    int bin0 = HBINS - 4 * (tid + 1);           // tid=0 covers the top 4 bins
    uint32_t c0 = 0, c1 = 0, c2 = 0, c3 = 0;
    for (int k = 0; k < HPARTS; ++k){
        const uint4 v = *(const uint4*)(pb + (size_t)k * HBINS + bin0);
        c0 += v.x; c1 += v.y; c2 += v.z; c3 += v.w;
    }
    uint32_t s = c0 + c1 + c2 + c3;
    __shared__ uint32_t ss[1024];
    uint32_t x = s;
    ss[tid] = x; __syncthreads();
    for (int d = 1; d < 1024; d <<= 1){
        uint32_t y = (tid >= d) ? ss[tid - d] : 0u;
        __syncthreads();
        x += y; ss[tid] = x;
        __syncthreads();
    }
    uint32_t incl = x, excl = x - s;
    if (excl < PRE_K && incl >= PRE_K){
        uint32_t c = excl;
        uint32_t cc[4] = {c0, c1, c2, c3};
        for (int j = 3; j >= 0; --j){            // walk bins descending by value
            c += cc[j];
            if (c >= PRE_K){ cut[img] = ((uint32_t)(bin0 + j)) << 20; break; }
        }
    }
}

// ---- compact candidates + fused gather/decode (wide grid hides HBM latency) ----
__global__ __launch_bounds__(256) void k_compact(const float* __restrict__ obj,
                                                 const uint32_t* __restrict__ cut,
                                                 uint32_t* __restrict__ cnt,
                                                 unsigned long long* __restrict__ cand,
                                                 const float* __restrict__ anchors,
                                                 const float* __restrict__ breg,
                                                 const int* __restrict__ pimh,
                                                 const int* __restrict__ pimw,
                                                 float4* __restrict__ cboxes,
                                                 float* __restrict__ cscores){
    int img   = blockIdx.x / CBLOCKS;
    int chunk = blockIdx.x - img * CBLOCKS;
    int base  = img * NUM + chunk * CHUNK;     // flat element base
    __shared__ uint32_t lcnt;
    __shared__ uint32_t gbase;
    __shared__ uint2 lbuf[CHUNK];              // (key, f)
    if (threadIdx.x == 0) lcnt = 0u;
    __syncthreads();
    uint32_t cutv = cut[img];
    #pragma unroll
    for (int it = 0; it < 2; ++it){
        int e = it * 1024 + (int)threadIdx.x * 4;   // element offset within chunk
        float4 v = *(const float4*)(obj + base + e);
        float vv[4] = {v.x, v.y, v.z, v.w};
        #pragma unroll
        for (int q = 0; q < 4; ++q){
            uint32_t k = fkey(vv[q]);
            if (k >= cutv){
                int r = chunk * CHUNK + e + q;       // index within image (a,h,w flat)
                int a = r / HWP, hw = r - a * HWP;
                uint32_t f = (uint32_t)(hw * AANCH + a);  // permute_and_flatten index
                uint32_t p = atomicAdd(&lcnt, 1u);        // LDS atomic: fast
                lbuf[p] = make_uint2(k, f);
            }
        }
    }
    __syncthreads();
    if (threadIdx.x == 0)
        gbase = (lcnt > 0u) ? atomicAdd(&cnt[img], lcnt) : 0u;  // ONE global atomic/block
    __syncthreads();
    uint32_t n = lcnt, gb = gbase;
    float imw = (float)(*pimw), imh = (float)(*pimh);
    const float CLIPV = 4.135166556742356f;     // log(1000/16)
    for (uint32_t t = threadIdx.x; t < n; t += 256u){
        uint32_t pos = gb + t;
        if (pos >= CAND_CAP) break;
        uint32_t key = lbuf[t].x, f = lbuf[t].y;
        // composite: [key:32][~f:18][slot:14] — order by (key desc, f asc); f unique
        cand[img * CAND_CAP + pos] = ((unsigned long long)key << 32)
            | ((unsigned long long)((~f) & 0x3FFFFu) << 14) | (unsigned long long)pos;
        // gather + decode + clip (latency hidden by 2016-block grid)
        float logit = keyf(key);
        float sc = 1.0f / (1.0f + expf(-logit));
        const float* an = anchors + ((size_t)img * NUM + f) * 4;
        float ax1 = an[0], ay1 = an[1], ax2 = an[2], ay2 = an[3];
        int a = (int)(f % AANCH); int hw = (int)(f / AANCH);
        size_t bbase = ((size_t)img * 12 + a * 4) * HWP + (size_t)hw;
        float dx = breg[bbase], dy = breg[bbase + HWP];
        float dw = breg[bbase + 2 * (size_t)HWP], dh = breg[bbase + 3 * (size_t)HWP];
        float aw = ax2 - ax1 + 1.0f, ah = ay2 - ay1 + 1.0f;
        float cx = ax1 + 0.5f * aw, cy = ay1 + 0.5f * ah;
        dw = fminf(dw, CLIPV); dh = fminf(dh, CLIPV);
        float pcx = dx * aw + cx, pcy = dy * ah + cy;
        float pw = expf(dw) * aw, ph = expf(dh) * ah;
        float x1 = pcx - 0.5f * pw, y1 = pcy - 0.5f * ph;
        float x2 = pcx + 0.5f * pw - 1.0f, y2 = pcy + 0.5f * ph - 1.0f;
        x1 = fminf(fmaxf(x1, 0.0f), imw - 1.0f);
        y1 = fminf(fmaxf(y1, 0.0f), imh - 1.0f);
        x2 = fminf(fmaxf(x2, 0.0f), imw - 1.0f);
        y2 = fminf(fmaxf(y2, 0.0f), imh - 1.0f);
        bool valid = ((x2 - x1 + 1.0f) >= 0.0f) && ((y2 - y1 + 1.0f) >= 0.0f);
        cboxes[img * CAND_CAP + pos] = make_float4(x1, y1, x2, y2);
        cscores[img * CAND_CAP + pos] = valid ? sc : -sc;   // sign bit = validity
    }
}

// ---- bitonic sort composites desc; rank->slot gather from L2-resident tables ----
__global__ __launch_bounds__(1024) void k_sort(
        const unsigned long long* __restrict__ cand, const uint32_t* __restrict__ cnt,
        const float4* __restrict__ cboxes, const float* __restrict__ cscores,
        float4* __restrict__ boxes_s, float* __restrict__ scores_s,
        uint32_t* __restrict__ rminit){
    int img = blockIdx.x, tid = threadIdx.x;
    __shared__ unsigned long long sd[CAND_CAP];
    uint32_t cl = min(cnt[img], (uint32_t)CAND_CAP);
    for (int t = tid; t < CAND_CAP; t += 1024)
        sd[t] = (t < (int)cl) ? cand[img * CAND_CAP + t] : 0ull;
    __syncthreads();
    for (uint32_t k = 2; k <= CAND_CAP; k <<= 1){
        for (uint32_t j = k >> 1; j > 0; j >>= 1){
            for (int t = tid; t < CAND_CAP; t += 1024){
                int ixj = t ^ (int)j;
                if (ixj > t){
                    unsigned long long a = sd[t], b = sd[ixj];
                    bool up = ((t & k) == 0);   // descending overall
                    if (up ? (a < b) : (a > b)){ sd[t] = b; sd[ixj] = a; }
                }
            }
            __syncthreads();
        }
    }
    for (int t = tid; t < PRE_K; t += 1024){
        uint32_t slot = (uint32_t)(sd[t] & 0x3FFFu);
        float4 b = cboxes[img * CAND_CAP + slot];
        float s = cscores[img * CAND_CAP + slot];
        boxes_s[img * ROWS + t] = b;
        scores_s[img * ROWS + t] = fabsf(s);
        if (s < 0.0f) atomicOr(&rminit[img * RWORDS + (t >> 5)], 1u << (t & 31));
    }
}

// ---- transposed 64x64 diagonal blocks: col_j bit i = (i suppresses j), i<j ----
__global__ __launch_bounds__(64) void k_diag(const float4* __restrict__ boxes_s,
                                             unsigned long long* __restrict__ colT){
    int img = blockIdx.x >> 5;
    int b   = blockIdx.x & 31;
    int j   = threadIdx.x;
    __shared__ float4 B[64];
    __shared__ float  AR[64];
    float4 bj = boxes_s[img * ROWS + b * 64 + j];
    float aj = (bj.z - bj.x + 1.0f) * (bj.w - bj.y + 1.0f);
    B[j] = bj; AR[j] = aj;
    __syncthreads();
    unsigned long long col = 0ull;
    #pragma unroll 8
    for (int i = 0; i < 64; ++i){
        float4 bi = B[i]; float ai = AR[i];
        float xx1 = fmaxf(bi.x, bj.x), yy1 = fmaxf(bi.y, bj.y);
        float xx2 = fminf(bi.z, bj.z), yy2 = fminf(bi.w, bj.w);
        float iw = fmaxf(xx2 - xx1 + 1.0f, 0.0f);
        float ih = fmaxf(yy2 - yy1 + 1.0f, 0.0f);
        float inter = iw * ih;
        bool pred = (i < j) && (inter > NMS_TH * (ai + aj - inter));
        col |= pred ? (1ull << i) : 0ull;
    }
    colT[(size_t)(img * 32 + b) * 64 + j] = col;
}

// ---- build upper-triangle IoU>thresh bitmask rows ----
// One wave per row-slice: lanes cover 64 consecutive j (conflict-free LDS reads),
// mask via __ballot, one uint64 store per 64-j block.
__global__ __launch_bounds__(1024) void k_mask(const float4* __restrict__ boxes_s,
                                               uint32_t* __restrict__ mask){
    int img = blockIdx.x >> 4;                 // 16 blocks per image
    int rc  = blockIdx.x & 15;
    int tid = threadIdx.x;
    int lane = tid & 63;
    int wv = tid >> 6;                         // 16 waves per block
    int gw = rc * 16 + wv;                     // 0..255 wave slot within image
    __shared__ float4 B[PRE_K];
    __shared__ float  AR[PRE_K];
    const float4* bp = boxes_s + img * ROWS;
    for (int t = tid; t < PRE_K; t += 1024){
        float4 b = bp[t]; B[t] = b;
        AR[t] = (b.z - b.x + 1.0f) * (b.w - b.y + 1.0f);
    }
    __syncthreads();
    uint32_t* M = mask + (size_t)img * ROWS * RWORDS;
    for (int i = gw; i < PRE_K; i += 256){
        float4 bi = B[i];                      // same address across wave: broadcast
        float ai = AR[i];
        unsigned long long* Mrow = (unsigned long long*)(M + (size_t)i * RWORDS);
        for (int jb = (i >> 6); jb < 32; ++jb){
            int j = (jb << 6) + lane;
            bool pred = false;
            if (j > i && j < PRE_K){
                float4 bj = B[j];
                float xx1 = fmaxf(bi.x, bj.x), yy1 = fmaxf(bi.y, bj.y);
                float xx2 = fminf(bi.z, bj.z), yy2 = fminf(bi.w, bj.w);
                float iw = fmaxf(xx2 - xx1 + 1.0f, 0.0f);
                float ih = fmaxf(yy2 - yy1 + 1.0f, 0.0f);
                float inter = iw * ih;
                pred = inter > NMS_TH * (ai + AR[j] - inter);
            }
            unsigned long long bm = __ballot(pred);
            if (lane == 0) Mrow[jb] = bm;
        }
    }
}

// ---- blocked greedy NMS scan: 32 phases of {ballot fixed-point + parallel apply} ----
__global__ __launch_bounds__(64) void k_scan(const uint32_t* __restrict__ mask,
                                             const unsigned long long* __restrict__ colT,
                                             const uint32_t* __restrict__ rminit,
                                             uint32_t* __restrict__ sel){
    int img = blockIdx.x; int lane = threadIdx.x;
    const uint32_t* M = mask + (size_t)img * ROWS * RWORDS;
    const unsigned long long* CT = colT + (size_t)img * 32 * 64;
    // initial removed: invalid boxes + padding rows >= PRE_K
    uint32_t rm = rminit[img * RWORDS + lane];
    if (lane == 62) rm |= 0xFFFF0000u;          // boxes 2000..2015
    if (lane == 63) rm  = 0xFFFFFFFFu;          // boxes 2016..2047
    unsigned long long col = CT[lane];          // block 0 columns
    #pragma unroll 1
    for (int b = 0; b < 32; ++b){
        // issue apply loads for this block (independent of resolution result)
        const uint32_t* Mb = M + (size_t)(b * 64) * RWORDS + lane;
        uint32_t mrow[64];
        #pragma unroll
        for (int i = 0; i < 64; ++i) mrow[i] = Mb[(size_t)i * RWORDS];
        // prefetch next block's columns
        unsigned long long coln = (b < 31) ? CT[(size_t)(b + 1) * 64 + lane] : 0ull;
        // incoming removed bits for this block
        uint32_t lo = __shfl(rm, 2 * b), hi = __shfl(rm, 2 * b + 1);
        unsigned long long inc = ((unsigned long long)hi << 32) | (unsigned long long)lo;
        bool alivej = ((inc >> lane) & 1ull) == 0ull;
        unsigned long long keep = ~inc;          // == ballot(alivej)
        #pragma unroll 1
        for (int it = 0; it < 66; ++it){         // converges in <=64 (prefix induction)
            bool ok = alivej && ((col & keep) == 0ull);
            unsigned long long nk = __ballot(ok);
            if (nk == keep) break;
            keep = nk;
        }
        // apply: OR mask rows of kept boxes into distributed removed state
        uint32_t acc = 0u;
        #pragma unroll
        for (int i = 0; i < 64; ++i)
            acc |= (keep & (1ull << i)) ? mrow[i] : 0u;
        rm |= (lane >= 2 * b) ? acc : 0u;        // words below diag are unwritten garbage
        // finalize this block's own removed words
        unsigned long long rmb = ~keep;
        if (lane == 2 * b)     rm = (uint32_t)rmb;
        if (lane == 2 * b + 1) rm = (uint32_t)(rmb >> 32);
        col = coln;
    }
    // kept = ~removed within [0, PRE_K)
    uint32_t inr = (lane < 62) ? 0xFFFFFFFFu : (lane == 62 ? 0x0000FFFFu : 0u);
    uint32_t kw = (~rm) & inr;
    uint32_t sw = rm & inr;
    uint32_t kc = __popc(kw);
    uint32_t x = kc;
    for (int d = 1; d < 64; d <<= 1){ uint32_t y = __shfl_up(x, d); if (lane >= d) x += y; }
    uint32_t kexcl = x - kc;
    uint32_t ktot = __shfl(x, 63);
    uint32_t* S = sel + img * 1024;
    uint32_t m = kw; uint32_t r = 0;
    while (m){
        int b = __ffs(m) - 1;
        uint32_t slot = kexcl + r;
        if (slot < POST_K) S[slot] = (uint32_t)(lane * 32 + b) | 0x80000000u;
        m &= m - 1; ++r;
    }
    if (ktot < POST_K){   // pad with suppressed positions in index order, score NEG
        uint32_t sc2 = __popc(sw);
        uint32_t x2 = sc2;
        for (int d = 1; d < 64; d <<= 1){ uint32_t y = __shfl_up(x2, d); if (lane >= d) x2 += y; }
        uint32_t sexcl = x2 - sc2;
        uint32_t m2 = sw; uint32_t r2 = 0;
        while (m2){
            int b = __ffs(m2) - 1;
            uint32_t slot = ktot + sexcl + r2;
            if (slot >= ktot && slot < POST_K) S[slot] = (uint32_t)(lane * 32 + b);
            m2 &= m2 - 1; ++r2;
        }
    }
}

// ---- write [N, 1000, 5] output ----
__global__ void k_out(const uint32_t* __restrict__ sel, const float4* __restrict__ boxes_s,
                      const float* __restrict__ scores_s, float* __restrict__ out){
    int t = blockIdx.x * blockDim.x + threadIdx.x;
    if (t >= NIMG * POST_K) return;
    int img = t / POST_K, s = t - img * POST_K;
    uint32_t v = sel[img * 1024 + s];
    uint32_t pos = v & 0x7FFFFFFFu;
    bool kept = (v >> 31) != 0;
    float4 b = boxes_s[img * ROWS + pos];
    float sc = kept ? scores_s[img * ROWS + pos] : NEGV;
    float* o = out + (size_t)t * 5;
    o[0] = b.x; o[1] = b.y; o[2] = b.z; o[3] = b.w; o[4] = sc;
}

extern "C" void kernel_launch(void* const* d_in, const int* in_sizes, int n_in,
                              void* d_out, int out_size, void* d_ws, size_t ws_size,
                              hipStream_t stream) {
    const float* anchors = (const float*)d_in[0];
    const float* obj     = (const float*)d_in[1];
    const float* breg    = (const float*)d_in[2];
    const int*   pimh    = (const int*)d_in[3];
    const int*   pimw    = (const int*)d_in[4];
    float* out = (float*)d_out;
    uint8_t* ws = (uint8_t*)d_ws;

    uint32_t*           part     = (uint32_t*)(ws + WS_HIST);
    unsigned long long* colT     = (unsigned long long*)(ws + WS_COLT);  // alias, post-binsel
    float4*             cboxes   = (float4*)(ws + WS_CBOX);              // alias, post-binsel
    float*              cscores  = (float*)(ws + WS_CSCO);               // alias, post-binsel
    uint32_t*           cut      = (uint32_t*)(ws + WS_CUT);
    uint32_t*           cnt      = (uint32_t*)(ws + WS_CNT);
    unsigned long long* cand     = (unsigned long long*)(ws + WS_CAND);
    float4*             boxes_s  = (float4*)(ws + WS_BOX);
    float*              scores_s = (float*)(ws + WS_SCO);
    uint32_t*           rminit   = (uint32_t*)(ws + WS_RMI);
    uint32_t*           sel      = (uint32_t*)(ws + WS_SEL);
    uint32_t*           mask     = (uint32_t*)(ws + WS_MASK);

    k_hist<<<NIMG * HPARTS, 1024, 0, stream>>>(obj, part, cnt, rminit);
    k_binsel<<<NIMG, 1024, 0, stream>>>(part, cut);
    k_compact<<<NIMG * CBLOCKS, 256, 0, stream>>>(obj, cut, cnt, cand,
                                                  anchors, breg, pimh, pimw,
                                                  cboxes, cscores);
    k_sort<<<NIMG, 1024, 0, stream>>>(cand, cnt, cboxes, cscores,
                                      boxes_s, scores_s, rminit);
    k_diag<<<NIMG * 32, 64, 0, stream>>>(boxes_s, colT);
    k_mask<<<NIMG * 16, 1024, 0, stream>>>(boxes_s, mask);
    k_scan<<<NIMG, 64, 0, stream>>>(mask, colT, rminit, sel);
    k_out<<<(NIMG * POST_K + 255) / 256, 256, 0, stream>>>(sel, boxes_s, scores_s, out);
}

// Round 7
// 168.616 us; speedup vs baseline: 7.3837x; 1.1137x over previous
//
#include <hip/hip_runtime.h>
#include <stdint.h>

// ---- problem constants (from setup_inputs) ----
#define NIMG 16
#define AANCH 3
#define HH 256
#define WW 336
#define HWP (HH*WW)            // 86016
#define NUM (AANCH*HWP)        // 258048 anchors per image
#define TOTAL (NIMG*NUM)       // 4128768
#define PRE_K 2000
#define POST_K 1000
#define NMS_TH 0.7f
#define NEGV -1e30f
#define CAND_CAP 4096
#define ROWS 2048              // padded row count for top-2000 arrays
#define RWORDS 64              // 32-bit mask words per NMS row (64*32 = 2048 bits)
#define CHUNK 2048             // elements per k_compact block
#define CBLOCKS (NUM / CHUNK)  // 126 blocks per image
#define HPARTS 16              // histogram partials per image
#define HBINS 4096             // 12-bit key prefix bins
#define HCHUNK (NUM / HPARTS)  // 16128 elements per hist block

// ---- workspace layout (bytes) ----
#define WS_HIST 0u             // 16 * 16 * 4096 * 4  = 4194304 (partial histograms)
                               // region is DEAD after k_binsel; aliased below:
#define WS_COLT 0u             //   colT   16*32*64*8 = 262144   (written by k_diag)
#define WS_CBOX 262144u        //   cboxes 16*4096*16 = 1048576  (written by k_compact)
#define WS_CSCO 1310720u       //   cscores 16*4096*4 = 262144   (written by k_compact)
#define WS_CUT  4194304u       // 16 * 4  (pad 256)
#define WS_CNT  4194560u       // 16 * 4  (pad 256)
#define WS_CAND 4194816u       // 16 * 4096 * 8       = 524288
#define WS_BOX  4719104u       // 16 * 2048 * 16      = 524288
#define WS_SCO  5243392u       // 16 * 2048 * 4       = 131072
#define WS_RMI  5374464u       // 16 * 64 * 4         = 4096
#define WS_SEL  5378560u       // 16 * 1024 * 4       = 65536
#define WS_MASK 5444096u       // 16 * 2048 * 64 * 4  = 8388608
// total ~13.8 MB

// monotonic float -> uint key (descending float == descending key)
__device__ __forceinline__ uint32_t fkey(float f){
    uint32_t b = __float_as_uint(f);
    return (b & 0x80000000u) ? ~b : (b | 0x80000000u);
}
__device__ __forceinline__ float keyf(uint32_t k){
    uint32_t b = (k & 0x80000000u) ? (k & 0x7FFFFFFFu) : ~k;
    return __uint_as_float(b);
}
__device__ __forceinline__ unsigned long long shflx64(unsigned long long x, int m){
    uint32_t lo = (uint32_t)x, hi = (uint32_t)(x >> 32);
    lo = __shfl_xor(lo, m); hi = __shfl_xor(hi, m);
    return ((unsigned long long)hi << 32) | (unsigned long long)lo;
}

// ---- per-block private LDS histogram -> global partials (no global atomics) ----
// Also zeroes cnt + rminit (block 0) since the old k_zero is gone.
__global__ __launch_bounds__(1024) void k_hist(const float* __restrict__ obj,
                                               uint32_t* __restrict__ part,
                                               uint32_t* __restrict__ cnt,
                                               uint32_t* __restrict__ rminit){
    int img = blockIdx.x >> 4;
    int blk = blockIdx.x & 15;
    int tid = threadIdx.x;
    if (blockIdx.x == 0){
        for (int i = tid; i < NIMG + NIMG * RWORDS; i += 1024){
            if (i < NIMG) cnt[i] = 0u;
            else          rminit[i - NIMG] = 0u;
        }
    }
    __shared__ uint32_t h[HBINS];
    #pragma unroll
    for (int i = 0; i < HBINS / 1024; ++i) h[tid + i * 1024] = 0u;
    __syncthreads();
    const float* base = obj + (size_t)img * NUM + (size_t)blk * HCHUNK;
    for (int e = tid * 4; e < HCHUNK; e += 4096){
        float4 v = *(const float4*)(base + e);
        atomicAdd(&h[fkey(v.x) >> 20], 1u);
        atomicAdd(&h[fkey(v.y) >> 20], 1u);
        atomicAdd(&h[fkey(v.z) >> 20], 1u);
        atomicAdd(&h[fkey(v.w) >> 20], 1u);
    }
    __syncthreads();
    uint32_t* p = part + ((size_t)blockIdx.x) * HBINS;
    #pragma unroll
    for (int i = 0; i < HBINS / 1024; ++i) p[tid + i * 1024] = h[tid + i * 1024];
}

// ---- merge partials, find the bin where top-count crosses PRE_K ----
__global__ __launch_bounds__(1024) void k_binsel(const uint32_t* __restrict__ part,
                                                 uint32_t* __restrict__ cut){
    int img = blockIdx.x, tid = threadIdx.x;
    const uint32_t* pb = part + (size_t)img * HPARTS * HBINS;
    int bin0 = HBINS - 4 * (tid + 1);           // tid=0 covers the top 4 bins
    uint32_t c0 = 0, c1 = 0, c2 = 0, c3 = 0;
    for (int k = 0; k < HPARTS; ++k){
        const uint4 v = *(const uint4*)(pb + (size_t)k * HBINS + bin0);
        c0 += v.x; c1 += v.y; c2 += v.z; c3 += v.w;
    }
    uint32_t s = c0 + c1 + c2 + c3;
    __shared__ uint32_t ss[1024];
    uint32_t x = s;
    ss[tid] = x; __syncthreads();
    for (int d = 1; d < 1024; d <<= 1){
        uint32_t y = (tid >= d) ? ss[tid - d] : 0u;
        __syncthreads();
        x += y; ss[tid] = x;
        __syncthreads();
    }
    uint32_t incl = x, excl = x - s;
    if (excl < PRE_K && incl >= PRE_K){
        uint32_t c = excl;
        uint32_t cc[4] = {c0, c1, c2, c3};
        for (int j = 3; j >= 0; --j){            // walk bins descending by value
            c += cc[j];
            if (c >= PRE_K){ cut[img] = ((uint32_t)(bin0 + j)) << 20; break; }
        }
    }
}

// ---- compact candidates + fused gather/decode (wide grid hides HBM latency) ----
__global__ __launch_bounds__(256) void k_compact(const float* __restrict__ obj,
                                                 const uint32_t* __restrict__ cut,
                                                 uint32_t* __restrict__ cnt,
                                                 unsigned long long* __restrict__ cand,
                                                 const float* __restrict__ anchors,
                                                 const float* __restrict__ breg,
                                                 const int* __restrict__ pimh,
                                                 const int* __restrict__ pimw,
                                                 float4* __restrict__ cboxes,
                                                 float* __restrict__ cscores){
    int img   = blockIdx.x / CBLOCKS;
    int chunk = blockIdx.x - img * CBLOCKS;
    int base  = img * NUM + chunk * CHUNK;     // flat element base
    __shared__ uint32_t lcnt;
    __shared__ uint32_t gbase;
    __shared__ uint2 lbuf[CHUNK];              // (key, f)
    if (threadIdx.x == 0) lcnt = 0u;
    __syncthreads();
    uint32_t cutv = cut[img];
    #pragma unroll
    for (int it = 0; it < 2; ++it){
        int e = it * 1024 + (int)threadIdx.x * 4;   // element offset within chunk
        float4 v = *(const float4*)(obj + base + e);
        float vv[4] = {v.x, v.y, v.z, v.w};
        #pragma unroll
        for (int q = 0; q < 4; ++q){
            uint32_t k = fkey(vv[q]);
            if (k >= cutv){
                int r = chunk * CHUNK + e + q;       // index within image (a,h,w flat)
                int a = r / HWP, hw = r - a * HWP;
                uint32_t f = (uint32_t)(hw * AANCH + a);  // permute_and_flatten index
                uint32_t p = atomicAdd(&lcnt, 1u);        // LDS atomic: fast
                lbuf[p] = make_uint2(k, f);
            }
        }
    }
    __syncthreads();
    if (threadIdx.x == 0)
        gbase = (lcnt > 0u) ? atomicAdd(&cnt[img], lcnt) : 0u;  // ONE global atomic/block
    __syncthreads();
    uint32_t n = lcnt, gb = gbase;
    float imw = (float)(*pimw), imh = (float)(*pimh);
    const float CLIPV = 4.135166556742356f;     // log(1000/16)
    for (uint32_t t = threadIdx.x; t < n; t += 256u){
        uint32_t pos = gb + t;
        if (pos >= CAND_CAP) break;
        uint32_t key = lbuf[t].x, f = lbuf[t].y;
        // composite: [key:32][~f:18][slot:14] — order by (key desc, f asc); f unique
        cand[img * CAND_CAP + pos] = ((unsigned long long)key << 32)
            | ((unsigned long long)((~f) & 0x3FFFFu) << 14) | (unsigned long long)pos;
        // gather + decode + clip (latency hidden by 2016-block grid)
        float logit = keyf(key);
        float sc = 1.0f / (1.0f + expf(-logit));
        const float* an = anchors + ((size_t)img * NUM + f) * 4;
        float ax1 = an[0], ay1 = an[1], ax2 = an[2], ay2 = an[3];
        int a = (int)(f % AANCH); int hw = (int)(f / AANCH);
        size_t bbase = ((size_t)img * 12 + a * 4) * HWP + (size_t)hw;
        float dx = breg[bbase], dy = breg[bbase + HWP];
        float dw = breg[bbase + 2 * (size_t)HWP], dh = breg[bbase + 3 * (size_t)HWP];
        float aw = ax2 - ax1 + 1.0f, ah = ay2 - ay1 + 1.0f;
        float cx = ax1 + 0.5f * aw, cy = ay1 + 0.5f * ah;
        dw = fminf(dw, CLIPV); dh = fminf(dh, CLIPV);
        float pcx = dx * aw + cx, pcy = dy * ah + cy;
        float pw = expf(dw) * aw, ph = expf(dh) * ah;
        float x1 = pcx - 0.5f * pw, y1 = pcy - 0.5f * ph;
        float x2 = pcx + 0.5f * pw - 1.0f, y2 = pcy + 0.5f * ph - 1.0f;
        x1 = fminf(fmaxf(x1, 0.0f), imw - 1.0f);
        y1 = fminf(fmaxf(y1, 0.0f), imh - 1.0f);
        x2 = fminf(fmaxf(x2, 0.0f), imw - 1.0f);
        y2 = fminf(fmaxf(y2, 0.0f), imh - 1.0f);
        bool valid = ((x2 - x1 + 1.0f) >= 0.0f) && ((y2 - y1 + 1.0f) >= 0.0f);
        cboxes[img * CAND_CAP + pos] = make_float4(x1, y1, x2, y2);
        cscores[img * CAND_CAP + pos] = valid ? sc : -sc;   // sign bit = validity
    }
}

// ---- register-resident bitonic sort (4 elems/thread) + rank->slot gather ----
// blocked layout: thread t holds elements 4t..4t+3.
//   j in {1,2}   : intra-thread register compare
//   j in {4..128}: intra-wave shfl_xor (no barrier)
//   j >= 256     : LDS exchange (10 phases, padded index kills bank conflicts)
#define SPAD(e) ((e) + ((e) >> 4))
__global__ __launch_bounds__(1024) void k_sort(
        const unsigned long long* __restrict__ cand, const uint32_t* __restrict__ cnt,
        const float4* __restrict__ cboxes, const float* __restrict__ cscores,
        float4* __restrict__ boxes_s, float* __restrict__ scores_s,
        uint32_t* __restrict__ rminit){
    int img = blockIdx.x, tid = threadIdx.x;
    __shared__ unsigned long long sd[CAND_CAP + (CAND_CAP >> 4)];
    uint32_t cl = min(cnt[img], (uint32_t)CAND_CAP);
    const unsigned long long* cp = cand + img * CAND_CAP;
    unsigned long long v[4];
    #pragma unroll
    for (int i = 0; i < 4; ++i){
        int e = 4 * tid + i;
        v[i] = (e < (int)cl) ? cp[e] : 0ull;
    }
    for (uint32_t k = 2; k <= CAND_CAP; k <<= 1){
        for (uint32_t j = k >> 1; j > 0; j >>= 1){
            if (j >= 256){
                #pragma unroll
                for (int i = 0; i < 4; ++i) sd[SPAD(4 * tid + i)] = v[i];
                __syncthreads();
                #pragma unroll
                for (int i = 0; i < 4; ++i){
                    int e = 4 * tid + i;
                    unsigned long long pv = sd[SPAD(e ^ (int)j)];
                    bool takeMax = (((e & j) == 0u) == ((e & k) == 0u));
                    v[i] = takeMax ? (v[i] > pv ? v[i] : pv)
                                   : (v[i] < pv ? v[i] : pv);
                }
                __syncthreads();
            } else if (j >= 4){
                int lm = (int)(j >> 2);
                #pragma unroll
                for (int i = 0; i < 4; ++i){
                    int e = 4 * tid + i;
                    unsigned long long pv = shflx64(v[i], lm);
                    bool takeMax = (((e & j) == 0u) == ((e & k) == 0u));
                    v[i] = takeMax ? (v[i] > pv ? v[i] : pv)
                                   : (v[i] < pv ? v[i] : pv);
                }
            } else {
                unsigned long long nv[4];
                #pragma unroll
                for (int i = 0; i < 4; ++i){
                    int e = 4 * tid + i;
                    unsigned long long pv = v[i ^ (int)j];
                    bool takeMax = (((e & j) == 0u) == ((e & k) == 0u));
                    nv[i] = takeMax ? (v[i] > pv ? v[i] : pv)
                                    : (v[i] < pv ? v[i] : pv);
                }
                #pragma unroll
                for (int i = 0; i < 4; ++i) v[i] = nv[i];
            }
        }
    }
    #pragma unroll
    for (int i = 0; i < 4; ++i){
        int t = 4 * tid + i;
        if (t < PRE_K){
            uint32_t slot = (uint32_t)(v[i] & 0x3FFFu);
            float4 b = cboxes[img * CAND_CAP + slot];
            float s = cscores[img * CAND_CAP + slot];
            boxes_s[img * ROWS + t] = b;
            scores_s[img * ROWS + t] = fabsf(s);
            if (s < 0.0f) atomicOr(&rminit[img * RWORDS + (t >> 5)], 1u << (t & 31));
        }
    }
}

// ---- transposed 64x64 diagonal blocks: col_j bit i = (i suppresses j), i<j ----
__global__ __launch_bounds__(64) void k_diag(const float4* __restrict__ boxes_s,
                                             unsigned long long* __restrict__ colT){
    int img = blockIdx.x >> 5;
    int b   = blockIdx.x & 31;
    int j   = threadIdx.x;
    __shared__ float4 B[64];
    __shared__ float  AR[64];
    float4 bj = boxes_s[img * ROWS + b * 64 + j];
    float aj = (bj.z - bj.x + 1.0f) * (bj.w - bj.y + 1.0f);
    B[j] = bj; AR[j] = aj;
    __syncthreads();
    unsigned long long col = 0ull;
    #pragma unroll 8
    for (int i = 0; i < 64; ++i){
        float4 bi = B[i]; float ai = AR[i];
        float xx1 = fmaxf(bi.x, bj.x), yy1 = fmaxf(bi.y, bj.y);
        float xx2 = fminf(bi.z, bj.z), yy2 = fminf(bi.w, bj.w);
        float iw = fmaxf(xx2 - xx1 + 1.0f, 0.0f);
        float ih = fmaxf(yy2 - yy1 + 1.0f, 0.0f);
        float inter = iw * ih;
        bool pred = (i < j) && (inter > NMS_TH * (ai + aj - inter));
        col |= pred ? (1ull << i) : 0ull;
    }
    colT[(size_t)(img * 32 + b) * 64 + j] = col;
}

// ---- build upper-triangle IoU>thresh bitmask rows ----
// One wave per row-slice: lanes cover 64 consecutive j (conflict-free LDS reads),
// mask via __ballot, one uint64 store per 64-j block.
__global__ __launch_bounds__(1024) void k_mask(const float4* __restrict__ boxes_s,
                                               uint32_t* __restrict__ mask){
    int img = blockIdx.x >> 4;                 // 16 blocks per image
    int rc  = blockIdx.x & 15;
    int tid = threadIdx.x;
    int lane = tid & 63;
    int wv = tid >> 6;                         // 16 waves per block
    int gw = rc * 16 + wv;                     // 0..255 wave slot within image
    __shared__ float4 B[PRE_K];
    __shared__ float  AR[PRE_K];
    const float4* bp = boxes_s + img * ROWS;
    for (int t = tid; t < PRE_K; t += 1024){
        float4 b = bp[t]; B[t] = b;
        AR[t] = (b.z - b.x + 1.0f) * (b.w - b.y + 1.0f);
    }
    __syncthreads();
    uint32_t* M = mask + (size_t)img * ROWS * RWORDS;
    for (int i = gw; i < PRE_K; i += 256){
        float4 bi = B[i];                      // same address across wave: broadcast
        float ai = AR[i];
        unsigned long long* Mrow = (unsigned long long*)(M + (size_t)i * RWORDS);
        for (int jb = (i >> 6); jb < 32; ++jb){
            int j = (jb << 6) + lane;
            bool pred = false;
            if (j > i && j < PRE_K){
                float4 bj = B[j];
                float xx1 = fmaxf(bi.x, bj.x), yy1 = fmaxf(bi.y, bj.y);
                float xx2 = fminf(bi.z, bj.z), yy2 = fminf(bi.w, bj.w);
                float iw = fmaxf(xx2 - xx1 + 1.0f, 0.0f);
                float ih = fmaxf(yy2 - yy1 + 1.0f, 0.0f);
                float inter = iw * ih;
                pred = inter > NMS_TH * (ai + AR[j] - inter);
            }
            unsigned long long bm = __ballot(pred);
            if (lane == 0) Mrow[jb] = bm;
        }
    }
}

// ---- blocked greedy NMS scan: 32 phases of {ballot fixed-point + parallel apply} ----
__global__ __launch_bounds__(64) void k_scan(const uint32_t* __restrict__ mask,
                                             const unsigned long long* __restrict__ colT,
                                             const uint32_t* __restrict__ rminit,
                                             uint32_t* __restrict__ sel){
    int img = blockIdx.x; int lane = threadIdx.x;
    const uint32_t* M = mask + (size_t)img * ROWS * RWORDS;
    const unsigned long long* CT = colT + (size_t)img * 32 * 64;
    // initial removed: invalid boxes + padding rows >= PRE_K
    uint32_t rm = rminit[img * RWORDS + lane];
    if (lane == 62) rm |= 0xFFFF0000u;          // boxes 2000..2015
    if (lane == 63) rm  = 0xFFFFFFFFu;          // boxes 2016..2047
    unsigned long long col = CT[lane];          // block 0 columns
    #pragma unroll 1
    for (int b = 0; b < 32; ++b){
        // issue apply loads for this block (independent of resolution result)
        const uint32_t* Mb = M + (size_t)(b * 64) * RWORDS + lane;
        uint32_t mrow[64];
        #pragma unroll
        for (int i = 0; i < 64; ++i) mrow[i] = Mb[(size_t)i * RWORDS];
        // prefetch next block's columns
        unsigned long long coln = (b < 31) ? CT[(size_t)(b + 1) * 64 + lane] : 0ull;
        // incoming removed bits for this block
        uint32_t lo = __shfl(rm, 2 * b), hi = __shfl(rm, 2 * b + 1);
        unsigned long long inc = ((unsigned long long)hi << 32) | (unsigned long long)lo;
        bool alivej = ((inc >> lane) & 1ull) == 0ull;
        unsigned long long keep = ~inc;          // == ballot(alivej)
        #pragma unroll 1
        for (int it = 0; it < 66; ++it){         // converges in <=64 (prefix induction)
            bool ok = alivej && ((col & keep) == 0ull);
            unsigned long long nk = __ballot(ok);
            if (nk == keep) break;
            keep = nk;
        }
        // apply: OR mask rows of kept boxes into distributed removed state
        uint32_t acc = 0u;
        #pragma unroll
        for (int i = 0; i < 64; ++i)
            acc |= (keep & (1ull << i)) ? mrow[i] : 0u;
        rm |= (lane >= 2 * b) ? acc : 0u;        // words below diag are unwritten garbage
        // finalize this block's own removed words
        unsigned long long rmb = ~keep;
        if (lane == 2 * b)     rm = (uint32_t)rmb;
        if (lane == 2 * b + 1) rm = (uint32_t)(rmb >> 32);
        col = coln;
    }
    // kept = ~removed within [0, PRE_K)
    uint32_t inr = (lane < 62) ? 0xFFFFFFFFu : (lane == 62 ? 0x0000FFFFu : 0u);
    uint32_t kw = (~rm) & inr;
    uint32_t sw = rm & inr;
    uint32_t kc = __popc(kw);
    uint32_t x = kc;
    for (int d = 1; d < 64; d <<= 1){ uint32_t y = __shfl_up(x, d); if (lane >= d) x += y; }
    uint32_t kexcl = x - kc;
    uint32_t ktot = __shfl(x, 63);
    uint32_t* S = sel + img * 1024;
    uint32_t m = kw; uint32_t r = 0;
    while (m){
        int b = __ffs(m) - 1;
        uint32_t slot = kexcl + r;
        if (slot < POST_K) S[slot] = (uint32_t)(lane * 32 + b) | 0x80000000u;
        m &= m - 1; ++r;
    }
    if (ktot < POST_K){   // pad with suppressed positions in index order, score NEG
        uint32_t sc2 = __popc(sw);
        uint32_t x2 = sc2;
        for (int d = 1; d < 64; d <<= 1){ uint32_t y = __shfl_up(x2, d); if (lane >= d) x2 += y; }
        uint32_t sexcl = x2 - sc2;
        uint32_t m2 = sw; uint32_t r2 = 0;
        while (m2){
            int b = __ffs(m2) - 1;
            uint32_t slot = ktot + sexcl + r2;
            if (slot >= ktot && slot < POST_K) S[slot] = (uint32_t)(lane * 32 + b);
            m2 &= m2 - 1; ++r2;
        }
    }
}

// ---- write [N, 1000, 5] output ----
__global__ void k_out(const uint32_t* __restrict__ sel, const float4* __restrict__ boxes_s,
                      const float* __restrict__ scores_s, float* __restrict__ out){
    int t = blockIdx.x * blockDim.x + threadIdx.x;
    if (t >= NIMG * POST_K) return;
    int img = t / POST_K, s = t - img * POST_K;
    uint32_t v = sel[img * 1024 + s];
    uint32_t pos = v & 0x7FFFFFFFu;
    bool kept = (v >> 31) != 0;
    float4 b = boxes_s[img * ROWS + pos];
    float sc = kept ? scores_s[img * ROWS + pos] : NEGV;
    float* o = out + (size_t)t * 5;
    o[0] = b.x; o[1] = b.y; o[2] = b.z; o[3] = b.w; o[4] = sc;
}

extern "C" void kernel_launch(void* const* d_in, const int* in_sizes, int n_in,
                              void* d_out, int out_size, void* d_ws, size_t ws_size,
                              hipStream_t stream) {
    const float* anchors = (const float*)d_in[0];
    const float* obj     = (const float*)d_in[1];
    const float* breg    = (const float*)d_in[2];
    const int*   pimh    = (const int*)d_in[3];
    const int*   pimw    = (const int*)d_in[4];
    float* out = (float*)d_out;
    uint8_t* ws = (uint8_t*)d_ws;

    uint32_t*           part     = (uint32_t*)(ws + WS_HIST);
    unsigned long long* colT     = (unsigned long long*)(ws + WS_COLT);  // alias, post-binsel
    float4*             cboxes   = (float4*)(ws + WS_CBOX);              // alias, post-binsel
    float*              cscores  = (float*)(ws + WS_CSCO);               // alias, post-binsel
    uint32_t*           cut      = (uint32_t*)(ws + WS_CUT);
    uint32_t*           cnt      = (uint32_t*)(ws + WS_CNT);
    unsigned long long* cand     = (unsigned long long*)(ws + WS_CAND);
    float4*             boxes_s  = (float4*)(ws + WS_BOX);
    float*              scores_s = (float*)(ws + WS_SCO);
    uint32_t*           rminit   = (uint32_t*)(ws + WS_RMI);
    uint32_t*           sel      = (uint32_t*)(ws + WS_SEL);
    uint32_t*           mask     = (uint32_t*)(ws + WS_MASK);

    k_hist<<<NIMG * HPARTS, 1024, 0, stream>>>(obj, part, cnt, rminit);
    k_binsel<<<NIMG, 1024, 0, stream>>>(part, cut);
    k_compact<<<NIMG * CBLOCKS, 256, 0, stream>>>(obj, cut, cnt, cand,
                                                  anchors, breg, pimh, pimw,
                                                  cboxes, cscores);
    k_sort<<<NIMG, 1024, 0, stream>>>(cand, cnt, cboxes, cscores,
                                      boxes_s, scores_s, rminit);
    k_diag<<<NIMG * 32, 64, 0, stream>>>(boxes_s, colT);
    k_mask<<<NIMG * 16, 1024, 0, stream>>>(boxes_s, mask);
    k_scan<<<NIMG, 64, 0, stream>>>(mask, colT, rminit, sel);
    k_out<<<(NIMG * POST_K + 255) / 256, 256, 0, stream>>>(sel, boxes_s, scores_s, out);
}